// Round 3
// baseline (611.750 us; speedup 1.0000x reference)
//
#include <hip/hip_runtime.h>
#include <stdint.h>

#define NN 10000
#define DIMV 256
#define HID 512
#define NEDGE 320000

typedef __attribute__((ext_vector_type(8))) short bf16x8;
typedef __attribute__((ext_vector_type(4))) float f32x4;
typedef __attribute__((ext_vector_type(4))) unsigned short u16x4;

__device__ __forceinline__ unsigned short f2bf(float f) {
  union { float f; unsigned int u; } c; c.f = f;
  return (unsigned short)((c.u + 0x7FFFu + ((c.u >> 16) & 1u)) >> 16);
}

__device__ __forceinline__ bf16x8 bzero8() {
  bf16x8 r;
#pragma unroll
  for (int i = 0; i < 8; ++i) r[i] = 0;
  return r;
}

__device__ __forceinline__ bf16x8 pack8(const float* x) {
  bf16x8 r;
#pragma unroll
  for (int i = 0; i < 8; ++i) r[i] = (short)f2bf(x[i]);
  return r;
}

// ---------------------------------------------------------------------------
// K0: convert weights fp32 -> bf16, transposed to [out][k] layout
// ---------------------------------------------------------------------------
__global__ void k_conv(const float* __restrict__ W1, const float* __restrict__ W2,
                       const float* __restrict__ Wl1, const float* __restrict__ Wl2,
                       unsigned short* __restrict__ W1T, unsigned short* __restrict__ W2T,
                       unsigned short* __restrict__ Wl1T, unsigned short* __restrict__ Wl2T) {
  int i = blockIdx.x * 256 + threadIdx.x;
  if (i < 131072) {
    { int k = i >> 9, o = i & 511; W1T[o * 256 + k] = f2bf(W1[i]); }
    { int k = i >> 8, o = i & 255; W2T[o * 512 + k] = f2bf(W2[i]); }
    if (i < 65536) {
      int k = i >> 8, o = i & 255;
      Wl1T[o * 256 + k] = f2bf(Wl1[i]);
      Wl2T[o * 256 + k] = f2bf(Wl2[i]);
    }
  }
}

// ---------------------------------------------------------------------------
// K1: v = relu(vc + relu(vc@W1+b1)@W2 + b2) -> v_rm [N][256], vT [256][N]
// ---------------------------------------------------------------------------
__launch_bounds__(256, 2)
__global__ void k_mlp(const float* __restrict__ vc,
                      const unsigned short* __restrict__ W1T, const float* __restrict__ b1,
                      const unsigned short* __restrict__ W2T, const float* __restrict__ b2,
                      unsigned short* __restrict__ v_rm, unsigned short* __restrict__ vT) {
  __shared__ __align__(16) char sm[65536];
  const int t = threadIdx.x;
  const int lane = t & 63, wid = t >> 6;
  const int wr = wid & 1, wc = wid >> 1;
  const int r0 = blockIdx.x * 32;

  {  // stage vc tile -> bf16
    const int row = t >> 3, grow = r0 + row;
#pragma unroll
    for (int q = 0; q < 4; ++q) {
      const int slot = (t & 7) * 4 + q;
      float buf[8] = {0.f, 0.f, 0.f, 0.f, 0.f, 0.f, 0.f, 0.f};
      if (grow < NN) {
        const float4 x0 = *(const float4*)(vc + (size_t)grow * DIMV + slot * 8);
        const float4 x1 = *(const float4*)(vc + (size_t)grow * DIMV + slot * 8 + 4);
        buf[0] = x0.x; buf[1] = x0.y; buf[2] = x0.z; buf[3] = x0.w;
        buf[4] = x1.x; buf[5] = x1.y; buf[6] = x1.z; buf[7] = x1.w;
      }
      *(bf16x8*)(sm + row * 512 + ((slot ^ (row & 7)) * 16)) = pack8(buf);
    }
  }

  f32x4 acc1[16];
#pragma unroll
  for (int i = 0; i < 16; ++i) acc1[i] = (f32x4){0.f, 0.f, 0.f, 0.f};

  for (int step = 0; step < 8; ++step) {
    __syncthreads();
#pragma unroll
    for (int rr = 0; rr < 2; ++rr) {
      const int c = t + rr * 256;
      const unsigned short* srcp = W1T + c * 256 + step * 32;
#pragma unroll
      for (int q = 0; q < 4; ++q) {
        bf16x8 w = *(const bf16x8*)(srcp + q * 8);
        *(bf16x8*)(sm + 16384 + c * 64 + ((q ^ ((c >> 1) & 3)) * 16)) = w;
      }
    }
    __syncthreads();
    const int arow = 16 * wr + (lane & 15);
    const int aslot = step * 4 + (lane >> 4);
    const bf16x8 af = *(const bf16x8*)(sm + arow * 512 + ((aslot ^ (arow & 7)) * 16));
#pragma unroll
    for (int ct = 0; ct < 16; ++ct) {
      const int c = 256 * wc + 16 * ct + (lane & 15);
      const bf16x8 bfr =
          *(const bf16x8*)(sm + 16384 + c * 64 + ((((lane >> 4)) ^ ((c >> 1) & 3)) * 16));
      acc1[ct] = __builtin_amdgcn_mfma_f32_16x16x32_bf16(af, bfr, acc1[ct], 0, 0, 0);
    }
  }
  __syncthreads();
#pragma unroll
  for (int ct = 0; ct < 16; ++ct) {
    const int c = 256 * wc + 16 * ct + (lane & 15);
    const float bb = b1[c];
#pragma unroll
    for (int r = 0; r < 4; ++r) {
      const int row = 16 * wr + (lane >> 4) * 4 + r;
      float v = fmaxf(acc1[ct][r] + bb, 0.f);
      const int slot = c >> 3;
      *(unsigned short*)(sm + 16384 + row * 1024 + ((slot ^ (row & 7)) * 16) + (c & 7) * 2) =
          f2bf(v);
    }
  }

  f32x4 acc2[8];
#pragma unroll
  for (int i = 0; i < 8; ++i) acc2[i] = (f32x4){0.f, 0.f, 0.f, 0.f};

  for (int step = 0; step < 16; ++step) {
    __syncthreads();
    {
      const int c = t;
      const unsigned short* srcp = W2T + c * 512 + step * 32;
#pragma unroll
      for (int q = 0; q < 4; ++q) {
        bf16x8 w = *(const bf16x8*)(srcp + q * 8);
        *(bf16x8*)(sm + 49152 + c * 64 + ((q ^ ((c >> 1) & 3)) * 16)) = w;
      }
    }
    __syncthreads();
    const int arow = 16 * wr + (lane & 15);
    const int aslot = step * 4 + (lane >> 4);
    const bf16x8 af = *(const bf16x8*)(sm + 16384 + arow * 1024 + ((aslot ^ (arow & 7)) * 16));
#pragma unroll
    for (int ct = 0; ct < 8; ++ct) {
      const int c = 128 * wc + 16 * ct + (lane & 15);
      const bf16x8 bfr =
          *(const bf16x8*)(sm + 49152 + c * 64 + ((((lane >> 4)) ^ ((c >> 1) & 3)) * 16));
      acc2[ct] = __builtin_amdgcn_mfma_f32_16x16x32_bf16(af, bfr, acc2[ct], 0, 0, 0);
    }
  }

  const int growbase = r0 + 16 * wr + (lane >> 4) * 4;
  if (growbase < NN) {
#pragma unroll
    for (int ct = 0; ct < 8; ++ct) {
      const int c = 128 * wc + 16 * ct + (lane & 15);
      const float bb = b2[c];
      u16x4 pk;
#pragma unroll
      for (int r = 0; r < 4; ++r) {
        const int grow = growbase + r;
        float v = acc2[ct][r] + bb + vc[(size_t)grow * DIMV + c];
        v = fmaxf(v, 0.f);
        const unsigned short hv = f2bf(v);
        v_rm[(size_t)grow * DIMV + c] = hv;
        pk[r] = hv;
      }
      *(u16x4*)(vT + (size_t)c * NN + growbase) = pk;
    }
  }
}

// ---------------------------------------------------------------------------
// K2: Av = A @ v.  BM=32, BN=256, split-K=S (runtime), chunk size Z (mult of 8).
// Register-prefetch double pipeline: issue loads for step+1 before MFMA of step.
// ---------------------------------------------------------------------------
__launch_bounds__(256, 4)
__global__ void k_av(const float* __restrict__ A, const unsigned short* __restrict__ vT,
                     float* __restrict__ avp, int Z) {
  __shared__ __align__(16) char sm[18432];  // smA [32][32] bf16 @0 (2KB), smV [256][32] @2048
  const int t = threadIdx.x, lane = t & 63, wid = t >> 6;
  const int wr = wid & 1, wc = wid >> 1;
  const int r0 = blockIdx.x * 32;
  const int s = blockIdx.y;
  const int kbase = s * Z;
  const int ksz = (NN - kbase < Z) ? (NN - kbase) : Z;  // multiple of 8
  const int nsteps = (ksz + 31) >> 5;
  float* outp = avp + (size_t)s * NN * DIMV;

  // A-staging roles (threads 0..127): i=row, qh=k-octet
  const int ai = t >> 2, aqh = t & 3;
  const int agrow = r0 + ai;

  f32x4 acc[8];
#pragma unroll
  for (int b = 0; b < 8; ++b) acc[b] = (f32x4){0.f, 0.f, 0.f, 0.f};

  float aR[8];
  bf16x8 vR[4];

  // --- prologue: load tile 0 into regs
  {
    const int k0 = 0;
    if (t < 128) {
#pragma unroll
      for (int z = 0; z < 8; ++z) aR[z] = 0.f;
      const int kk = k0 + aqh * 8;
      if (agrow < NN && kk < ksz) {
        const float* p = A + (size_t)agrow * NN + kbase + kk;
        const float4 x0 = *(const float4*)p;
        const float4 x1 = *(const float4*)(p + 4);
        aR[0] = x0.x; aR[1] = x0.y; aR[2] = x0.z; aR[3] = x0.w;
        aR[4] = x1.x; aR[5] = x1.y; aR[6] = x1.z; aR[7] = x1.w;
      }
    }
    const unsigned short* srcp = vT + (size_t)t * NN + kbase + k0;
#pragma unroll
    for (int q = 0; q < 4; ++q)
      vR[q] = (k0 + q * 8 < ksz) ? *(const bf16x8*)(srcp + q * 8) : bzero8();
  }

  for (int step = 0; step < nsteps; ++step) {
    __syncthreads();  // previous LDS reads complete
    if (t < 128)
      *(bf16x8*)(sm + ai * 64 + ((aqh ^ ((ai >> 1) & 3)) * 16)) = pack8(aR);
    {
      const int c = t;
#pragma unroll
      for (int q = 0; q < 4; ++q)
        *(bf16x8*)(sm + 2048 + c * 64 + ((q ^ ((c >> 1) & 3)) * 16)) = vR[q];
    }
    __syncthreads();  // LDS tile ready

    // issue next tile's global loads (results consumed only at next iteration)
    if (step + 1 < nsteps) {
      const int k0 = (step + 1) * 32;
      if (t < 128) {
        const int kk = k0 + aqh * 8;
        if (agrow < NN && kk < ksz) {
          const float* p = A + (size_t)agrow * NN + kbase + kk;
          const float4 x0 = *(const float4*)p;
          const float4 x1 = *(const float4*)(p + 4);
          aR[0] = x0.x; aR[1] = x0.y; aR[2] = x0.z; aR[3] = x0.w;
          aR[4] = x1.x; aR[5] = x1.y; aR[6] = x1.z; aR[7] = x1.w;
        } else {
#pragma unroll
          for (int z = 0; z < 8; ++z) aR[z] = 0.f;
        }
      }
      const unsigned short* srcp = vT + (size_t)t * NN + kbase + k0;
#pragma unroll
      for (int q = 0; q < 4; ++q)
        vR[q] = (k0 + q * 8 < ksz) ? *(const bf16x8*)(srcp + q * 8) : bzero8();
    }

    // compute current tile from LDS
    const int ar = 16 * wr + (lane & 15);
    const bf16x8 af =
        *(const bf16x8*)(sm + ar * 64 + ((((lane >> 4)) ^ ((ar >> 1) & 3)) * 16));
#pragma unroll
    for (int ct = 0; ct < 8; ++ct) {
      const int c = 128 * wc + 16 * ct + (lane & 15);
      const bf16x8 bfr =
          *(const bf16x8*)(sm + 2048 + c * 64 + ((((lane >> 4)) ^ ((c >> 1) & 3)) * 16));
      acc[ct] = __builtin_amdgcn_mfma_f32_16x16x32_bf16(af, bfr, acc[ct], 0, 0, 0);
    }
  }

  const int growbase = r0 + 16 * wr + (lane >> 4) * 4;
  if (growbase < NN) {
#pragma unroll
    for (int ct = 0; ct < 8; ++ct) {
      const int c = 128 * wc + 16 * ct + (lane & 15);
#pragma unroll
      for (int r = 0; r < 4; ++r)
        outp[(size_t)(growbase + r) * DIMV + c] = acc[ct][r];
    }
  }
}

// ---------------------------------------------------------------------------
// K3: v2 = relu(v@Wl1+bl1) + relu((sum_p avp[p])@Wl2+bl2); writes v2 and d_out
// ---------------------------------------------------------------------------
__launch_bounds__(256, 2)
__global__ void k_out(const unsigned short* __restrict__ v_rm, const float* __restrict__ avp,
                      const unsigned short* __restrict__ Wl1T, const float* __restrict__ bl1,
                      const unsigned short* __restrict__ Wl2T, const float* __restrict__ bl2,
                      float* __restrict__ v2, float* __restrict__ outb, int S) {
  __shared__ __align__(16) char sm[65536];
  const int t = threadIdx.x, lane = t & 63, wid = t >> 6;
  const int wr = wid & 1, wc = wid >> 1;
  const int r0 = blockIdx.x * 32;

  {
    const int row = t >> 3, grow = r0 + row;
#pragma unroll
    for (int q = 0; q < 4; ++q) {
      const int slot = (t & 7) * 4 + q;
      bf16x8 w = (grow < NN) ? *(const bf16x8*)(v_rm + (size_t)grow * DIMV + slot * 8) : bzero8();
      *(bf16x8*)(sm + row * 512 + ((slot ^ (row & 7)) * 16)) = w;
    }
#pragma unroll
    for (int q = 0; q < 4; ++q) {
      const int slot = (t & 7) * 4 + q;
      float buf[8] = {0.f, 0.f, 0.f, 0.f, 0.f, 0.f, 0.f, 0.f};
      if (grow < NN) {
        for (int p = 0; p < S; ++p) {
          const float* pp = avp + (size_t)p * NN * DIMV + (size_t)grow * DIMV + slot * 8;
          const float4 a0 = *(const float4*)pp, a1 = *(const float4*)(pp + 4);
          buf[0] += a0.x; buf[1] += a0.y; buf[2] += a0.z; buf[3] += a0.w;
          buf[4] += a1.x; buf[5] += a1.y; buf[6] += a1.z; buf[7] += a1.w;
        }
      }
      *(bf16x8*)(sm + 16384 + row * 512 + ((slot ^ (row & 7)) * 16)) = pack8(buf);
    }
  }

  f32x4 acc1[8], acc2[8];
#pragma unroll
  for (int i = 0; i < 8; ++i) {
    acc1[i] = (f32x4){0.f, 0.f, 0.f, 0.f};
    acc2[i] = (f32x4){0.f, 0.f, 0.f, 0.f};
  }

  for (int step = 0; step < 8; ++step) {
    __syncthreads();
    {
      const int c = t;
      const unsigned short* s1 = Wl1T + c * 256 + step * 32;
      const unsigned short* s2 = Wl2T + c * 256 + step * 32;
#pragma unroll
      for (int q = 0; q < 4; ++q) {
        const int ps = (q ^ ((c >> 1) & 3)) * 16;
        *(bf16x8*)(sm + 32768 + c * 64 + ps) = *(const bf16x8*)(s1 + q * 8);
        *(bf16x8*)(sm + 49152 + c * 64 + ps) = *(const bf16x8*)(s2 + q * 8);
      }
    }
    __syncthreads();
    const int arow = 16 * wr + (lane & 15);
    const int aslot = step * 4 + (lane >> 4);
    const bf16x8 a1 = *(const bf16x8*)(sm + arow * 512 + ((aslot ^ (arow & 7)) * 16));
    const bf16x8 a2 = *(const bf16x8*)(sm + 16384 + arow * 512 + ((aslot ^ (arow & 7)) * 16));
#pragma unroll
    for (int ct = 0; ct < 8; ++ct) {
      const int c = 128 * wc + 16 * ct + (lane & 15);
      const int bs = (((lane >> 4)) ^ ((c >> 1) & 3)) * 16;
      acc1[ct] = __builtin_amdgcn_mfma_f32_16x16x32_bf16(
          a1, *(const bf16x8*)(sm + 32768 + c * 64 + bs), acc1[ct], 0, 0, 0);
      acc2[ct] = __builtin_amdgcn_mfma_f32_16x16x32_bf16(
          a2, *(const bf16x8*)(sm + 49152 + c * 64 + bs), acc2[ct], 0, 0, 0);
    }
  }

  const int growbase = r0 + 16 * wr + (lane >> 4) * 4;
  if (growbase < NN) {
#pragma unroll
    for (int ct = 0; ct < 8; ++ct) {
      const int c = 128 * wc + 16 * ct + (lane & 15);
      const float u1 = bl1[c], u2 = bl2[c];
#pragma unroll
      for (int r = 0; r < 4; ++r) {
        const float x = fmaxf(acc1[ct][r] + u1, 0.f) + fmaxf(acc2[ct][r] + u2, 0.f);
        v2[(size_t)(growbase + r) * DIMV + c] = x;
        outb[(size_t)(growbase + r) * DIMV + c] = x;
      }
    }
  }
}

// ---------------------------------------------------------------------------
// K4a: histogram of dst
// ---------------------------------------------------------------------------
__global__ void k_hist(const int* __restrict__ dst, int* __restrict__ counts) {
  const int e = blockIdx.x * 256 + threadIdx.x;
  if (e < NEDGE) atomicAdd(&counts[dst[e]], 1);
}

// ---------------------------------------------------------------------------
// K4b: exclusive scan of counts[10000] -> offsets[10001], cursor copy
// ---------------------------------------------------------------------------
__global__ void k_scan(const int* __restrict__ counts, int* __restrict__ offsets,
                       int* __restrict__ cursor) {
  __shared__ int sm[1024];
  __shared__ int carry;
  const int t = threadIdx.x;
  if (t == 0) carry = 0;
  __syncthreads();
  for (int base = 0; base < NN; base += 1024) {
    const int i = base + t;
    const int x = (i < NN) ? counts[i] : 0;
    sm[t] = x;
    __syncthreads();
    for (int off = 1; off < 1024; off <<= 1) {
      int y = (t >= off) ? sm[t - off] : 0;
      __syncthreads();
      sm[t] += y;
      __syncthreads();
    }
    const int excl = sm[t] - x + carry;
    if (i < NN) { offsets[i] = excl; cursor[i] = excl; }
    __syncthreads();
    if (t == 1023) carry += sm[1023];
    __syncthreads();
  }
  if (t == 0) offsets[NN] = carry;
}

// ---------------------------------------------------------------------------
// K4c: fill buckets with src ids
// ---------------------------------------------------------------------------
__global__ void k_fill(const int* __restrict__ src, const int* __restrict__ dst,
                       int* __restrict__ cursor, int* __restrict__ srcbuf) {
  const int e = blockIdx.x * 256 + threadIdx.x;
  if (e < NEDGE) {
    const int pos = atomicAdd(&cursor[dst[e]], 1);
    srcbuf[pos] = src[e];
  }
}

// ---------------------------------------------------------------------------
// K4d: gather-sum, one wave per dst node, 4-deep unrolled for MLP.
// ---------------------------------------------------------------------------
__launch_bounds__(256)
__global__ void k_gather(const float* __restrict__ v2, const int* __restrict__ offsets,
                         const int* __restrict__ srcbuf, float* __restrict__ outb) {
  const int n = (blockIdx.x * 256 + threadIdx.x) >> 6;
  if (n >= NN) return;
  const int lane = threadIdx.x & 63;
  const int beg = offsets[n], end = offsets[n + 1];
  float4 a0 = {0.f, 0.f, 0.f, 0.f}, a1 = a0, a2 = a0, a3 = a0;
  int j = beg;
  for (; j + 4 <= end; j += 4) {
    const int s0 = srcbuf[j], s1 = srcbuf[j + 1], s2 = srcbuf[j + 2], s3 = srcbuf[j + 3];
    const float4 x0 = *(const float4*)(v2 + (size_t)s0 * DIMV + lane * 4);
    const float4 x1 = *(const float4*)(v2 + (size_t)s1 * DIMV + lane * 4);
    const float4 x2 = *(const float4*)(v2 + (size_t)s2 * DIMV + lane * 4);
    const float4 x3 = *(const float4*)(v2 + (size_t)s3 * DIMV + lane * 4);
    a0.x += x0.x; a0.y += x0.y; a0.z += x0.z; a0.w += x0.w;
    a1.x += x1.x; a1.y += x1.y; a1.z += x1.z; a1.w += x1.w;
    a2.x += x2.x; a2.y += x2.y; a2.z += x2.z; a2.w += x2.w;
    a3.x += x3.x; a3.y += x3.y; a3.z += x3.z; a3.w += x3.w;
  }
  for (; j < end; ++j) {
    const int s0 = srcbuf[j];
    const float4 x0 = *(const float4*)(v2 + (size_t)s0 * DIMV + lane * 4);
    a0.x += x0.x; a0.y += x0.y; a0.z += x0.z; a0.w += x0.w;
  }
  a0.x += a1.x + a2.x + a3.x; a0.y += a1.y + a2.y + a3.y;
  a0.z += a1.z + a2.z + a3.z; a0.w += a1.w + a2.w + a3.w;
  float* o = outb + (size_t)n * DIMV + lane * 4;
  float4 cur = *(const float4*)o;
  cur.x += a0.x; cur.y += a0.y; cur.z += a0.z; cur.w += a0.w;
  *(float4*)o = cur;
}

// ---------------------------------------------------------------------------
extern "C" void kernel_launch(void* const* d_in, const int* in_sizes, int n_in,
                              void* d_out, int out_size, void* d_ws, size_t ws_size,
                              hipStream_t stream) {
  const float* vc  = (const float*)d_in[0];
  const float* A   = (const float*)d_in[1];
  const int*   src = (const int*)d_in[2];
  const int*   dst = (const int*)d_in[3];
  const float* W1  = (const float*)d_in[4];
  const float* b1  = (const float*)d_in[5];
  const float* W2  = (const float*)d_in[6];
  const float* b2  = (const float*)d_in[7];
  const float* Wl1 = (const float*)d_in[8];
  const float* bl1 = (const float*)d_in[9];
  const float* Wl2 = (const float*)d_in[10];
  const float* bl2 = (const float*)d_in[11];
  float* outb = (float*)d_out;
  char* ws = (char*)d_ws;

  // static carve
  unsigned short* W1T  = (unsigned short*)(ws + 0);          // 512x256 bf16
  unsigned short* W2T  = (unsigned short*)(ws + 262144);     // 256x512
  unsigned short* Wl1T = (unsigned short*)(ws + 524288);     // 256x256
  unsigned short* Wl2T = (unsigned short*)(ws + 655360);     // 256x256
  unsigned short* vT   = (unsigned short*)(ws + 786432);     // [256][10000] (dead after k_av)
  unsigned short* v_rm = (unsigned short*)(ws + 5906432);    // [10000][256] bf16
  const size_t PBYTES = (size_t)NN * DIMV * sizeof(float);   // 10,240,000 per partial
  float*          avp  = (float*)(ws + 11026432);            // S x [10000][256] f32
  // split-K factor chosen from available ws (v2 sits after the S partials)
  int S = 2;
  if (ws_size > 11026432 + PBYTES) {
    size_t smax = (ws_size - 11026432 - PBYTES) / PBYTES;
    S = (int)(smax < 2 ? 2 : (smax > 8 ? 8 : smax));
  }
  float* v2 = (float*)(ws + 11026432 + (size_t)S * PBYTES);
  const int Z = (((NN + S - 1) / S) + 7) & ~7;  // chunk size, multiple of 8

  // CSR arrays alias the vT region (only used after k_av has consumed vT)
  int* counts  = (int*)(ws + 786432);
  int* offsets = (int*)(ws + 829440);
  int* cursor  = (int*)(ws + 872448);
  int* srcbuf  = (int*)(ws + 915456);

  hipLaunchKernelGGL(k_conv, dim3(512), dim3(256), 0, stream,
                     W1, W2, Wl1, Wl2, W1T, W2T, Wl1T, Wl2T);
  hipLaunchKernelGGL(k_mlp, dim3(313), dim3(256), 0, stream,
                     vc, W1T, b1, W2T, b2, v_rm, vT);
  hipLaunchKernelGGL(k_av, dim3(313, S), dim3(256), 0, stream, A, vT, avp, Z);

  // CSR build (vT is dead from here on)
  hipMemsetAsync(counts, 0, NN * sizeof(int), stream);
  hipLaunchKernelGGL(k_hist, dim3((NEDGE + 255) / 256), dim3(256), 0, stream, dst, counts);
  hipLaunchKernelGGL(k_scan, dim3(1), dim3(1024), 0, stream, counts, offsets, cursor);
  hipLaunchKernelGGL(k_fill, dim3((NEDGE + 255) / 256), dim3(256), 0, stream,
                     src, dst, cursor, srcbuf);

  hipLaunchKernelGGL(k_out, dim3(313), dim3(256), 0, stream,
                     v_rm, avp, Wl1T, bl1, Wl2T, bl2, v2, outb, S);
  hipLaunchKernelGGL(k_gather, dim3((NN * 64 + 255) / 256), dim3(256), 0, stream,
                     v2, offsets, srcbuf, outb);
}

// Round 4
// 504.708 us; speedup vs baseline: 1.2121x; 1.2121x over previous
//
#include <hip/hip_runtime.h>
#include <stdint.h>

#define NN 10000
#define DIMV 256
#define HID 512
#define NEDGE 320000
#define VTP 10016  // padded k-stride of vT (zeros in [10000,10016))
#define SPLIT 4
#define ZCHUNK 2496  // multiple of 32; last chunk = 10000-3*2496 = 2512 (78*32+16)

typedef __attribute__((ext_vector_type(8))) short bf16x8;
typedef __attribute__((ext_vector_type(4))) float f32x4;
typedef __attribute__((ext_vector_type(4))) unsigned short u16x4;

__device__ __forceinline__ unsigned short f2bf(float f) {
  union { float f; unsigned int u; } c; c.f = f;
  return (unsigned short)((c.u + 0x7FFFu + ((c.u >> 16) & 1u)) >> 16);
}

__device__ __forceinline__ bf16x8 bzero8() {
  bf16x8 r;
#pragma unroll
  for (int i = 0; i < 8; ++i) r[i] = 0;
  return r;
}

__device__ __forceinline__ bf16x8 pack8(const float* x) {
  bf16x8 r;
#pragma unroll
  for (int i = 0; i < 8; ++i) r[i] = (short)f2bf(x[i]);
  return r;
}

// 8 fp32 (two float4) -> bf16x8 via v_cvt_pk_bf16_f32 (RNE, matches f2bf)
__device__ __forceinline__ bf16x8 cvt8(const float4 a, const float4 b) {
  union { unsigned int u[4]; bf16x8 v; } r;
  asm("v_cvt_pk_bf16_f32 %0, %1, %2" : "=v"(r.u[0]) : "v"(a.x), "v"(a.y));
  asm("v_cvt_pk_bf16_f32 %0, %1, %2" : "=v"(r.u[1]) : "v"(a.z), "v"(a.w));
  asm("v_cvt_pk_bf16_f32 %0, %1, %2" : "=v"(r.u[2]) : "v"(b.x), "v"(b.y));
  asm("v_cvt_pk_bf16_f32 %0, %1, %2" : "=v"(r.u[3]) : "v"(b.z), "v"(b.w));
  return r.v;
}

// ---------------------------------------------------------------------------
// K0: convert weights fp32 -> bf16 transposed; zero vT's k-pad
// ---------------------------------------------------------------------------
__global__ void k_conv(const float* __restrict__ W1, const float* __restrict__ W2,
                       const float* __restrict__ Wl1, const float* __restrict__ Wl2,
                       unsigned short* __restrict__ W1T, unsigned short* __restrict__ W2T,
                       unsigned short* __restrict__ Wl1T, unsigned short* __restrict__ Wl2T,
                       unsigned short* __restrict__ vT) {
  int i = blockIdx.x * 256 + threadIdx.x;
  if (i < 131072) {
    { int k = i >> 9, o = i & 511; W1T[o * 256 + k] = f2bf(W1[i]); }
    { int k = i >> 8, o = i & 255; W2T[o * 512 + k] = f2bf(W2[i]); }
    if (i < 65536) {
      int k = i >> 8, o = i & 255;
      Wl1T[o * 256 + k] = f2bf(Wl1[i]);
      Wl2T[o * 256 + k] = f2bf(Wl2[i]);
    }
    if (i < 4096) {  // zero the vT pad columns
      int c = i >> 4, kk = i & 15;
      vT[(size_t)c * VTP + 10000 + kk] = 0;
    }
  }
}

// ---------------------------------------------------------------------------
// K1: v = relu(vc + relu(vc@W1+b1)@W2 + b2) -> v_rm [N][256], vT [256][VTP]
// ---------------------------------------------------------------------------
__launch_bounds__(256, 2)
__global__ void k_mlp(const float* __restrict__ vc,
                      const unsigned short* __restrict__ W1T, const float* __restrict__ b1,
                      const unsigned short* __restrict__ W2T, const float* __restrict__ b2,
                      unsigned short* __restrict__ v_rm, unsigned short* __restrict__ vT) {
  __shared__ __align__(16) char sm[65536];
  const int t = threadIdx.x;
  const int lane = t & 63, wid = t >> 6;
  const int wr = wid & 1, wc = wid >> 1;
  const int r0 = blockIdx.x * 32;

  {  // stage vc tile -> bf16
    const int row = t >> 3, grow = r0 + row;
#pragma unroll
    for (int q = 0; q < 4; ++q) {
      const int slot = (t & 7) * 4 + q;
      float buf[8] = {0.f, 0.f, 0.f, 0.f, 0.f, 0.f, 0.f, 0.f};
      if (grow < NN) {
        const float4 x0 = *(const float4*)(vc + (size_t)grow * DIMV + slot * 8);
        const float4 x1 = *(const float4*)(vc + (size_t)grow * DIMV + slot * 8 + 4);
        buf[0] = x0.x; buf[1] = x0.y; buf[2] = x0.z; buf[3] = x0.w;
        buf[4] = x1.x; buf[5] = x1.y; buf[6] = x1.z; buf[7] = x1.w;
      }
      *(bf16x8*)(sm + row * 512 + ((slot ^ (row & 7)) * 16)) = pack8(buf);
    }
  }

  f32x4 acc1[16];
#pragma unroll
  for (int i = 0; i < 16; ++i) acc1[i] = (f32x4){0.f, 0.f, 0.f, 0.f};

  for (int step = 0; step < 8; ++step) {
    __syncthreads();
#pragma unroll
    for (int rr = 0; rr < 2; ++rr) {
      const int c = t + rr * 256;
      const unsigned short* srcp = W1T + c * 256 + step * 32;
#pragma unroll
      for (int q = 0; q < 4; ++q) {
        bf16x8 w = *(const bf16x8*)(srcp + q * 8);
        *(bf16x8*)(sm + 16384 + c * 64 + ((q ^ ((c >> 1) & 3)) * 16)) = w;
      }
    }
    __syncthreads();
    const int arow = 16 * wr + (lane & 15);
    const int aslot = step * 4 + (lane >> 4);
    const bf16x8 af = *(const bf16x8*)(sm + arow * 512 + ((aslot ^ (arow & 7)) * 16));
#pragma unroll
    for (int ct = 0; ct < 16; ++ct) {
      const int c = 256 * wc + 16 * ct + (lane & 15);
      const bf16x8 bfr =
          *(const bf16x8*)(sm + 16384 + c * 64 + ((((lane >> 4)) ^ ((c >> 1) & 3)) * 16));
      acc1[ct] = __builtin_amdgcn_mfma_f32_16x16x32_bf16(af, bfr, acc1[ct], 0, 0, 0);
    }
  }
  __syncthreads();
#pragma unroll
  for (int ct = 0; ct < 16; ++ct) {
    const int c = 256 * wc + 16 * ct + (lane & 15);
    const float bb = b1[c];
#pragma unroll
    for (int r = 0; r < 4; ++r) {
      const int row = 16 * wr + (lane >> 4) * 4 + r;
      float v = fmaxf(acc1[ct][r] + bb, 0.f);
      const int slot = c >> 3;
      *(unsigned short*)(sm + 16384 + row * 1024 + ((slot ^ (row & 7)) * 16) + (c & 7) * 2) =
          f2bf(v);
    }
  }

  f32x4 acc2[8];
#pragma unroll
  for (int i = 0; i < 8; ++i) acc2[i] = (f32x4){0.f, 0.f, 0.f, 0.f};

  for (int step = 0; step < 16; ++step) {
    __syncthreads();
    {
      const int c = t;
      const unsigned short* srcp = W2T + c * 512 + step * 32;
#pragma unroll
      for (int q = 0; q < 4; ++q) {
        bf16x8 w = *(const bf16x8*)(srcp + q * 8);
        *(bf16x8*)(sm + 49152 + c * 64 + ((q ^ ((c >> 1) & 3)) * 16)) = w;
      }
    }
    __syncthreads();
    const int arow = 16 * wr + (lane & 15);
    const int aslot = step * 4 + (lane >> 4);
    const bf16x8 af = *(const bf16x8*)(sm + 16384 + arow * 1024 + ((aslot ^ (arow & 7)) * 16));
#pragma unroll
    for (int ct = 0; ct < 8; ++ct) {
      const int c = 128 * wc + 16 * ct + (lane & 15);
      const bf16x8 bfr =
          *(const bf16x8*)(sm + 49152 + c * 64 + ((((lane >> 4)) ^ ((c >> 1) & 3)) * 16));
      acc2[ct] = __builtin_amdgcn_mfma_f32_16x16x32_bf16(af, bfr, acc2[ct], 0, 0, 0);
    }
  }

  const int growbase = r0 + 16 * wr + (lane >> 4) * 4;
  if (growbase < NN) {
#pragma unroll
    for (int ct = 0; ct < 8; ++ct) {
      const int c = 128 * wc + 16 * ct + (lane & 15);
      const float bb = b2[c];
      u16x4 pk;
#pragma unroll
      for (int r = 0; r < 4; ++r) {
        const int grow = growbase + r;
        float v = acc2[ct][r] + bb + vc[(size_t)grow * DIMV + c];
        v = fmaxf(v, 0.f);
        const unsigned short hv = f2bf(v);
        v_rm[(size_t)grow * DIMV + c] = hv;
        pk[r] = hv;
      }
      *(u16x4*)(vT + (size_t)c * VTP + growbase) = pk;
    }
  }
}

// ---------------------------------------------------------------------------
// K2: Av = A @ v.  Register-direct MFMA GEMM: NO LDS, NO barriers.
// BM=32, BN=256; 4 waves each own all 32 rows x 64 cols. 2-deep pipeline.
// grid (313, SPLIT). A-frags loaded fp32->cvt_pk->bf16; B-frags from vT.
// ---------------------------------------------------------------------------
__launch_bounds__(256, 4)
__global__ void k_av(const float* __restrict__ A, const unsigned short* __restrict__ vT,
                     float* __restrict__ avp) {
  const int t = threadIdx.x, lane = t & 63, wid = t >> 6;
  const int r0 = blockIdx.x * 32;
  const int s = blockIdx.y;
  const int kbase = s * ZCHUNK;
  const int ksz = (s == SPLIT - 1) ? (NN - (SPLIT - 1) * ZCHUNK) : ZCHUNK;
  const int nfull = ksz >> 5;   // full 32-k steps (78 for all chunks)
  const int ktail = ksz & 31;   // 16 on the last chunk only
  float* outp = avp + (size_t)s * NN * DIMV;

  const int lr = lane & 15;
  const int kl = (lane >> 4) * 8;
  const int row0 = min(r0 + lr, NN - 1);
  const int row1 = min(r0 + 16 + lr, NN - 1);
  const float* pa0 = A + (size_t)row0 * NN + kbase + kl;
  const float* pa1 = A + (size_t)row1 * NN + kbase + kl;
  const int cb = wid * 64 + lr;  // this wave's column base (+ct*16)
  const unsigned short* pv0 = vT + (size_t)cb * VTP + kbase + kl;
  const unsigned short* pv1 = pv0 + (size_t)16 * VTP;
  const unsigned short* pv2 = pv0 + (size_t)32 * VTP;
  const unsigned short* pv3 = pv0 + (size_t)48 * VTP;

  f32x4 acc00 = {0.f, 0.f, 0.f, 0.f}, acc01 = acc00, acc02 = acc00, acc03 = acc00;
  f32x4 acc10 = acc00, acc11 = acc00, acc12 = acc00, acc13 = acc00;

  float4 xA0, xA1, xA2, xA3, xB0, xB1, xB2, xB3;
  bf16x8 yA0, yA1, yA2, yA3, yB0, yB1, yB2, yB3;

#define LOADSET(xa0, xa1, xa2, xa3, yb0, yb1, yb2, yb3)        \
  do {                                                         \
    xa0 = *(const float4*)pa0; xa1 = *(const float4*)(pa0 + 4);\
    xa2 = *(const float4*)pa1; xa3 = *(const float4*)(pa1 + 4);\
    yb0 = *(const bf16x8*)pv0; yb1 = *(const bf16x8*)pv1;      \
    yb2 = *(const bf16x8*)pv2; yb3 = *(const bf16x8*)pv3;      \
    pa0 += 32; pa1 += 32; pv0 += 32; pv1 += 32; pv2 += 32; pv3 += 32; \
  } while (0)

#define COMPSET(xa0, xa1, xa2, xa3, yb0, yb1, yb2, yb3)                     \
  do {                                                                      \
    const bf16x8 af0 = cvt8(xa0, xa1);                                      \
    const bf16x8 af1 = cvt8(xa2, xa3);                                      \
    acc00 = __builtin_amdgcn_mfma_f32_16x16x32_bf16(af0, yb0, acc00, 0, 0, 0); \
    acc01 = __builtin_amdgcn_mfma_f32_16x16x32_bf16(af0, yb1, acc01, 0, 0, 0); \
    acc02 = __builtin_amdgcn_mfma_f32_16x16x32_bf16(af0, yb2, acc02, 0, 0, 0); \
    acc03 = __builtin_amdgcn_mfma_f32_16x16x32_bf16(af0, yb3, acc03, 0, 0, 0); \
    acc10 = __builtin_amdgcn_mfma_f32_16x16x32_bf16(af1, yb0, acc10, 0, 0, 0); \
    acc11 = __builtin_amdgcn_mfma_f32_16x16x32_bf16(af1, yb1, acc11, 0, 0, 0); \
    acc12 = __builtin_amdgcn_mfma_f32_16x16x32_bf16(af1, yb2, acc12, 0, 0, 0); \
    acc13 = __builtin_amdgcn_mfma_f32_16x16x32_bf16(af1, yb3, acc13, 0, 0, 0); \
  } while (0)

  // 2-deep software pipeline over nfull steps (no barriers: waves free-run)
  int step = 0;
  LOADSET(xA0, xA1, xA2, xA3, yA0, yA1, yA2, yA3);
  while (step < nfull) {
    if (step + 1 < nfull) LOADSET(xB0, xB1, xB2, xB3, yB0, yB1, yB2, yB3);
    COMPSET(xA0, xA1, xA2, xA3, yA0, yA1, yA2, yA3);
    ++step;
    if (step >= nfull) break;
    if (step + 1 < nfull) LOADSET(xA0, xA1, xA2, xA3, yA0, yA1, yA2, yA3);
    COMPSET(xB0, xB1, xB2, xB3, yB0, yB1, yB2, yB3);
    ++step;
  }

  if (ktail) {  // last chunk only: 16 valid k; vT pad supplies zeros for k>=10000
    float4 z4 = {0.f, 0.f, 0.f, 0.f};
    float4 ta0 = z4, ta1 = z4, ta2 = z4, ta3 = z4;
    if (kl < ktail) {
      ta0 = *(const float4*)pa0; ta1 = *(const float4*)(pa0 + 4);
      ta2 = *(const float4*)pa1; ta3 = *(const float4*)(pa1 + 4);
    }
    const bf16x8 tb0 = *(const bf16x8*)pv0;
    const bf16x8 tb1 = *(const bf16x8*)pv1;
    const bf16x8 tb2 = *(const bf16x8*)pv2;
    const bf16x8 tb3 = *(const bf16x8*)pv3;
    COMPSET(ta0, ta1, ta2, ta3, tb0, tb1, tb2, tb3);
  }

#undef LOADSET
#undef COMPSET

#define STQ(ACC, gb, ct)                                      \
  do {                                                        \
    float* o = outp + (size_t)(gb) * DIMV + cb + (ct) * 16;   \
    o[0] = ACC[0]; o += DIMV; o[0] = ACC[1]; o += DIMV;       \
    o[0] = ACC[2]; o += DIMV; o[0] = ACC[3];                  \
  } while (0)

  const int gb0 = r0 + (lane >> 4) * 4;
  if (gb0 < NN) { STQ(acc00, gb0, 0); STQ(acc01, gb0, 1); STQ(acc02, gb0, 2); STQ(acc03, gb0, 3); }
  const int gb1 = gb0 + 16;
  if (gb1 < NN) { STQ(acc10, gb1, 0); STQ(acc11, gb1, 1); STQ(acc12, gb1, 2); STQ(acc13, gb1, 3); }
#undef STQ
}

// ---------------------------------------------------------------------------
// K3: v2 = relu(v@Wl1+bl1) + relu((sum_p avp[p])@Wl2+bl2); writes v2 and d_out
// ---------------------------------------------------------------------------
__launch_bounds__(256, 2)
__global__ void k_out(const unsigned short* __restrict__ v_rm, const float* __restrict__ avp,
                      const unsigned short* __restrict__ Wl1T, const float* __restrict__ bl1,
                      const unsigned short* __restrict__ Wl2T, const float* __restrict__ bl2,
                      float* __restrict__ v2, float* __restrict__ outb, int S) {
  __shared__ __align__(16) char sm[65536];
  const int t = threadIdx.x, lane = t & 63, wid = t >> 6;
  const int wr = wid & 1, wc = wid >> 1;
  const int r0 = blockIdx.x * 32;

  {
    const int row = t >> 3, grow = r0 + row;
#pragma unroll
    for (int q = 0; q < 4; ++q) {
      const int slot = (t & 7) * 4 + q;
      bf16x8 w = (grow < NN) ? *(const bf16x8*)(v_rm + (size_t)grow * DIMV + slot * 8) : bzero8();
      *(bf16x8*)(sm + row * 512 + ((slot ^ (row & 7)) * 16)) = w;
    }
#pragma unroll
    for (int q = 0; q < 4; ++q) {
      const int slot = (t & 7) * 4 + q;
      float buf[8] = {0.f, 0.f, 0.f, 0.f, 0.f, 0.f, 0.f, 0.f};
      if (grow < NN) {
        for (int p = 0; p < S; ++p) {
          const float* pp = avp + (size_t)p * NN * DIMV + (size_t)grow * DIMV + slot * 8;
          const float4 a0 = *(const float4*)pp, a1 = *(const float4*)(pp + 4);
          buf[0] += a0.x; buf[1] += a0.y; buf[2] += a0.z; buf[3] += a0.w;
          buf[4] += a1.x; buf[5] += a1.y; buf[6] += a1.z; buf[7] += a1.w;
        }
      }
      *(bf16x8*)(sm + 16384 + row * 512 + ((slot ^ (row & 7)) * 16)) = pack8(buf);
    }
  }

  f32x4 acc1[8], acc2[8];
#pragma unroll
  for (int i = 0; i < 8; ++i) {
    acc1[i] = (f32x4){0.f, 0.f, 0.f, 0.f};
    acc2[i] = (f32x4){0.f, 0.f, 0.f, 0.f};
  }

  for (int step = 0; step < 8; ++step) {
    __syncthreads();
    {
      const int c = t;
      const unsigned short* s1 = Wl1T + c * 256 + step * 32;
      const unsigned short* s2 = Wl2T + c * 256 + step * 32;
#pragma unroll
      for (int q = 0; q < 4; ++q) {
        const int ps = (q ^ ((c >> 1) & 3)) * 16;
        *(bf16x8*)(sm + 32768 + c * 64 + ps) = *(const bf16x8*)(s1 + q * 8);
        *(bf16x8*)(sm + 49152 + c * 64 + ps) = *(const bf16x8*)(s2 + q * 8);
      }
    }
    __syncthreads();
    const int arow = 16 * wr + (lane & 15);
    const int aslot = step * 4 + (lane >> 4);
    const bf16x8 a1 = *(const bf16x8*)(sm + arow * 512 + ((aslot ^ (arow & 7)) * 16));
    const bf16x8 a2 = *(const bf16x8*)(sm + 16384 + arow * 512 + ((aslot ^ (arow & 7)) * 16));
#pragma unroll
    for (int ct = 0; ct < 8; ++ct) {
      const int c = 128 * wc + 16 * ct + (lane & 15);
      const int bs = (((lane >> 4)) ^ ((c >> 1) & 3)) * 16;
      acc1[ct] = __builtin_amdgcn_mfma_f32_16x16x32_bf16(
          a1, *(const bf16x8*)(sm + 32768 + c * 64 + bs), acc1[ct], 0, 0, 0);
      acc2[ct] = __builtin_amdgcn_mfma_f32_16x16x32_bf16(
          a2, *(const bf16x8*)(sm + 49152 + c * 64 + bs), acc2[ct], 0, 0, 0);
    }
  }

  const int growbase = r0 + 16 * wr + (lane >> 4) * 4;
  if (growbase < NN) {
#pragma unroll
    for (int ct = 0; ct < 8; ++ct) {
      const int c = 128 * wc + 16 * ct + (lane & 15);
      const float u1 = bl1[c], u2 = bl2[c];
#pragma unroll
      for (int r = 0; r < 4; ++r) {
        const float x = fmaxf(acc1[ct][r] + u1, 0.f) + fmaxf(acc2[ct][r] + u2, 0.f);
        v2[(size_t)(growbase + r) * DIMV + c] = x;
        outb[(size_t)(growbase + r) * DIMV + c] = x;
      }
    }
  }
}

// ---------------------------------------------------------------------------
// K4a: histogram of dst
// ---------------------------------------------------------------------------
__global__ void k_hist(const int* __restrict__ dst, int* __restrict__ counts) {
  const int e = blockIdx.x * 256 + threadIdx.x;
  if (e < NEDGE) atomicAdd(&counts[dst[e]], 1);
}

// ---------------------------------------------------------------------------
// K4b: exclusive scan of counts[10000] -> offsets[10001], cursor copy
// ---------------------------------------------------------------------------
__global__ void k_scan(const int* __restrict__ counts, int* __restrict__ offsets,
                       int* __restrict__ cursor) {
  __shared__ int sm[1024];
  __shared__ int carry;
  const int t = threadIdx.x;
  if (t == 0) carry = 0;
  __syncthreads();
  for (int base = 0; base < NN; base += 1024) {
    const int i = base + t;
    const int x = (i < NN) ? counts[i] : 0;
    sm[t] = x;
    __syncthreads();
    for (int off = 1; off < 1024; off <<= 1) {
      int y = (t >= off) ? sm[t - off] : 0;
      __syncthreads();
      sm[t] += y;
      __syncthreads();
    }
    const int excl = sm[t] - x + carry;
    if (i < NN) { offsets[i] = excl; cursor[i] = excl; }
    __syncthreads();
    if (t == 1023) carry += sm[1023];
    __syncthreads();
  }
  if (t == 0) offsets[NN] = carry;
}

// ---------------------------------------------------------------------------
// K4c: fill buckets with src ids
// ---------------------------------------------------------------------------
__global__ void k_fill(const int* __restrict__ src, const int* __restrict__ dst,
                       int* __restrict__ cursor, int* __restrict__ srcbuf) {
  const int e = blockIdx.x * 256 + threadIdx.x;
  if (e < NEDGE) {
    const int pos = atomicAdd(&cursor[dst[e]], 1);
    srcbuf[pos] = src[e];
  }
}

// ---------------------------------------------------------------------------
// K4d: gather-sum, one wave per dst node, 4-deep unrolled.
// ---------------------------------------------------------------------------
__launch_bounds__(256)
__global__ void k_gather(const float* __restrict__ v2, const int* __restrict__ offsets,
                         const int* __restrict__ srcbuf, float* __restrict__ outb) {
  const int n = (blockIdx.x * 256 + threadIdx.x) >> 6;
  if (n >= NN) return;
  const int lane = threadIdx.x & 63;
  const int beg = offsets[n], end = offsets[n + 1];
  float4 a0 = {0.f, 0.f, 0.f, 0.f}, a1 = a0, a2 = a0, a3 = a0;
  int j = beg;
  for (; j + 4 <= end; j += 4) {
    const int s0 = srcbuf[j], s1 = srcbuf[j + 1], s2 = srcbuf[j + 2], s3 = srcbuf[j + 3];
    const float4 x0 = *(const float4*)(v2 + (size_t)s0 * DIMV + lane * 4);
    const float4 x1 = *(const float4*)(v2 + (size_t)s1 * DIMV + lane * 4);
    const float4 x2 = *(const float4*)(v2 + (size_t)s2 * DIMV + lane * 4);
    const float4 x3 = *(const float4*)(v2 + (size_t)s3 * DIMV + lane * 4);
    a0.x += x0.x; a0.y += x0.y; a0.z += x0.z; a0.w += x0.w;
    a1.x += x1.x; a1.y += x1.y; a1.z += x1.z; a1.w += x1.w;
    a2.x += x2.x; a2.y += x2.y; a2.z += x2.z; a2.w += x2.w;
    a3.x += x3.x; a3.y += x3.y; a3.z += x3.z; a3.w += x3.w;
  }
  for (; j < end; ++j) {
    const int s0 = srcbuf[j];
    const float4 x0 = *(const float4*)(v2 + (size_t)s0 * DIMV + lane * 4);
    a0.x += x0.x; a0.y += x0.y; a0.z += x0.z; a0.w += x0.w;
  }
  a0.x += a1.x + a2.x + a3.x; a0.y += a1.y + a2.y + a3.y;
  a0.z += a1.z + a2.z + a3.z; a0.w += a1.w + a2.w + a3.w;
  float* o = outb + (size_t)n * DIMV + lane * 4;
  float4 cur = *(const float4*)o;
  cur.x += a0.x; cur.y += a0.y; cur.z += a0.z; cur.w += a0.w;
  *(float4*)o = cur;
}

// ---------------------------------------------------------------------------
extern "C" void kernel_launch(void* const* d_in, const int* in_sizes, int n_in,
                              void* d_out, int out_size, void* d_ws, size_t ws_size,
                              hipStream_t stream) {
  const float* vc  = (const float*)d_in[0];
  const float* A   = (const float*)d_in[1];
  const int*   src = (const int*)d_in[2];
  const int*   dst = (const int*)d_in[3];
  const float* W1  = (const float*)d_in[4];
  const float* b1  = (const float*)d_in[5];
  const float* W2  = (const float*)d_in[6];
  const float* b2  = (const float*)d_in[7];
  const float* Wl1 = (const float*)d_in[8];
  const float* bl1 = (const float*)d_in[9];
  const float* Wl2 = (const float*)d_in[10];
  const float* bl2 = (const float*)d_in[11];
  float* outb = (float*)d_out;
  char* ws = (char*)d_ws;

  // carve (bytes):
  unsigned short* W1T  = (unsigned short*)(ws + 0);          // 512x256 bf16
  unsigned short* W2T  = (unsigned short*)(ws + 262144);     // 256x512
  unsigned short* Wl1T = (unsigned short*)(ws + 524288);     // 256x256
  unsigned short* Wl2T = (unsigned short*)(ws + 655360);     // 256x256
  unsigned short* vT   = (unsigned short*)(ws + 786432);     // [256][VTP] bf16 (dead after k_av)
  unsigned short* v_rm = (unsigned short*)(ws + 5914624);    // [10000][256] bf16
  float*          avp  = (float*)(ws + 11034624);            // SPLIT x [10000][256] f32
  float*          v2   = (float*)(ws + 11034624 + (size_t)SPLIT * NN * DIMV * 4);

  // CSR arrays alias the vT region (only used after k_av has consumed vT)
  int* counts  = (int*)(ws + 786432);
  int* offsets = (int*)(ws + 829440);
  int* cursor  = (int*)(ws + 872448);
  int* srcbuf  = (int*)(ws + 915456);

  hipLaunchKernelGGL(k_conv, dim3(512), dim3(256), 0, stream,
                     W1, W2, Wl1, Wl2, W1T, W2T, Wl1T, Wl2T, vT);
  hipLaunchKernelGGL(k_mlp, dim3(313), dim3(256), 0, stream,
                     vc, W1T, b1, W2T, b2, v_rm, vT);
  hipLaunchKernelGGL(k_av, dim3(313, SPLIT), dim3(256), 0, stream, A, vT, avp);

  // CSR build (vT is dead from here on)
  hipMemsetAsync(counts, 0, NN * sizeof(int), stream);
  hipLaunchKernelGGL(k_hist, dim3((NEDGE + 255) / 256), dim3(256), 0, stream, dst, counts);
  hipLaunchKernelGGL(k_scan, dim3(1), dim3(1024), 0, stream, counts, offsets, cursor);
  hipLaunchKernelGGL(k_fill, dim3((NEDGE + 255) / 256), dim3(256), 0, stream,
                     src, dst, cursor, srcbuf);

  hipLaunchKernelGGL(k_out, dim3(313), dim3(256), 0, stream,
                     v_rm, avp, Wl1T, bl1, Wl2T, bl2, v2, outb, SPLIT);
  hipLaunchKernelGGL(k_gather, dim3((NN * 64 + 255) / 256), dim3(256), 0, stream,
                     v2, offsets, srcbuf, outb);
}

// Round 5
// 440.531 us; speedup vs baseline: 1.3887x; 1.1457x over previous
//
#include <hip/hip_runtime.h>
#include <stdint.h>

#define NN 10000
#define DIMV 256
#define HID 512
#define NEDGE 320000
#define SPLIT 8
#define ZCH 1248      // 39*32 per chunk; last chunk = 10000-7*1248 = 1264 = 39*32+16
#define NKT 313       // 313 k-tiles of 32 (tile 312 padded with zeros for k>=10000)

typedef __attribute__((ext_vector_type(8))) short bf16x8;
typedef __attribute__((ext_vector_type(4))) float f32x4;
typedef __attribute__((ext_vector_type(4))) unsigned short u16x4;

__device__ __forceinline__ unsigned short f2bf(float f) {
  union { float f; unsigned int u; } c; c.f = f;
  return (unsigned short)((c.u + 0x7FFFu + ((c.u >> 16) & 1u)) >> 16);
}

__device__ __forceinline__ bf16x8 bzero8() {
  bf16x8 r;
#pragma unroll
  for (int i = 0; i < 8; ++i) r[i] = 0;
  return r;
}

__device__ __forceinline__ bf16x8 pack8(const float* x) {
  bf16x8 r;
#pragma unroll
  for (int i = 0; i < 8; ++i) r[i] = (short)f2bf(x[i]);
  return r;
}

// two f32x4 -> bf16x8 via v_cvt_pk_bf16_f32 (RNE, matches f2bf)
__device__ __forceinline__ bf16x8 cvt8v(const f32x4 a, const f32x4 b) {
  union { unsigned int u[4]; bf16x8 v; } r;
  asm("v_cvt_pk_bf16_f32 %0, %1, %2" : "=v"(r.u[0]) : "v"(a[0]), "v"(a[1]));
  asm("v_cvt_pk_bf16_f32 %0, %1, %2" : "=v"(r.u[1]) : "v"(a[2]), "v"(a[3]));
  asm("v_cvt_pk_bf16_f32 %0, %1, %2" : "=v"(r.u[2]) : "v"(b[0]), "v"(b[1]));
  asm("v_cvt_pk_bf16_f32 %0, %1, %2" : "=v"(r.u[3]) : "v"(b[2]), "v"(b[3]));
  return r.v;
}

// ---------------------------------------------------------------------------
// K0: convert weights fp32 -> bf16 transposed; zero vB's k-pad (tile 312)
// ---------------------------------------------------------------------------
__global__ void k_conv(const float* __restrict__ W1, const float* __restrict__ W2,
                       const float* __restrict__ Wl1, const float* __restrict__ Wl2,
                       unsigned short* __restrict__ W1T, unsigned short* __restrict__ W2T,
                       unsigned short* __restrict__ Wl1T, unsigned short* __restrict__ Wl2T,
                       unsigned short* __restrict__ vB) {
  int i = blockIdx.x * 256 + threadIdx.x;
  if (i < 131072) {
    { int k = i >> 9, o = i & 511; W1T[o * 256 + k] = f2bf(W1[i]); }
    { int k = i >> 8, o = i & 255; W2T[o * 512 + k] = f2bf(W2[i]); }
    if (i < 65536) {
      int k = i >> 8, o = i & 255;
      Wl1T[o * 256 + k] = f2bf(Wl1[i]);
      Wl2T[o * 256 + k] = f2bf(Wl2[i]);
    }
    if (i < 4096) {  // zero vB tile 312, kk in [16,32)
      int c = i >> 4, kk = 16 + (i & 15);
      vB[(size_t)312 * 8192 + c * 32 + kk] = 0;
    }
  }
}

// ---------------------------------------------------------------------------
// K1: v = relu(vc + relu(vc@W1+b1)@W2 + b2) -> v_rm [N][256] and
//     vB [313 ktiles][256 cols][32 k] bf16 (fragment-ready B of A@v)
// ---------------------------------------------------------------------------
__launch_bounds__(256, 2)
__global__ void k_mlp(const float* __restrict__ vc,
                      const unsigned short* __restrict__ W1T, const float* __restrict__ b1,
                      const unsigned short* __restrict__ W2T, const float* __restrict__ b2,
                      unsigned short* __restrict__ v_rm, unsigned short* __restrict__ vB) {
  __shared__ __align__(16) char sm[65536];
  const int t = threadIdx.x;
  const int lane = t & 63, wid = t >> 6;
  const int wr = wid & 1, wc = wid >> 1;
  const int r0 = blockIdx.x * 32;

  {  // stage vc tile -> bf16
    const int row = t >> 3, grow = r0 + row;
#pragma unroll
    for (int q = 0; q < 4; ++q) {
      const int slot = (t & 7) * 4 + q;
      float buf[8] = {0.f, 0.f, 0.f, 0.f, 0.f, 0.f, 0.f, 0.f};
      if (grow < NN) {
        const float4 x0 = *(const float4*)(vc + (size_t)grow * DIMV + slot * 8);
        const float4 x1 = *(const float4*)(vc + (size_t)grow * DIMV + slot * 8 + 4);
        buf[0] = x0.x; buf[1] = x0.y; buf[2] = x0.z; buf[3] = x0.w;
        buf[4] = x1.x; buf[5] = x1.y; buf[6] = x1.z; buf[7] = x1.w;
      }
      *(bf16x8*)(sm + row * 512 + ((slot ^ (row & 7)) * 16)) = pack8(buf);
    }
  }

  f32x4 acc1[16];
#pragma unroll
  for (int i = 0; i < 16; ++i) acc1[i] = (f32x4){0.f, 0.f, 0.f, 0.f};

  for (int step = 0; step < 8; ++step) {
    __syncthreads();
#pragma unroll
    for (int rr = 0; rr < 2; ++rr) {
      const int c = t + rr * 256;
      const unsigned short* srcp = W1T + c * 256 + step * 32;
#pragma unroll
      for (int q = 0; q < 4; ++q) {
        bf16x8 w = *(const bf16x8*)(srcp + q * 8);
        *(bf16x8*)(sm + 16384 + c * 64 + ((q ^ ((c >> 1) & 3)) * 16)) = w;
      }
    }
    __syncthreads();
    const int arow = 16 * wr + (lane & 15);
    const int aslot = step * 4 + (lane >> 4);
    const bf16x8 af = *(const bf16x8*)(sm + arow * 512 + ((aslot ^ (arow & 7)) * 16));
#pragma unroll
    for (int ct = 0; ct < 16; ++ct) {
      const int c = 256 * wc + 16 * ct + (lane & 15);
      const bf16x8 bfr =
          *(const bf16x8*)(sm + 16384 + c * 64 + ((((lane >> 4)) ^ ((c >> 1) & 3)) * 16));
      acc1[ct] = __builtin_amdgcn_mfma_f32_16x16x32_bf16(af, bfr, acc1[ct], 0, 0, 0);
    }
  }
  __syncthreads();
#pragma unroll
  for (int ct = 0; ct < 16; ++ct) {
    const int c = 256 * wc + 16 * ct + (lane & 15);
    const float bb = b1[c];
#pragma unroll
    for (int r = 0; r < 4; ++r) {
      const int row = 16 * wr + (lane >> 4) * 4 + r;
      float v = fmaxf(acc1[ct][r] + bb, 0.f);
      const int slot = c >> 3;
      *(unsigned short*)(sm + 16384 + row * 1024 + ((slot ^ (row & 7)) * 16) + (c & 7) * 2) =
          f2bf(v);
    }
  }

  f32x4 acc2[8];
#pragma unroll
  for (int i = 0; i < 8; ++i) acc2[i] = (f32x4){0.f, 0.f, 0.f, 0.f};

  for (int step = 0; step < 16; ++step) {
    __syncthreads();
    {
      const int c = t;
      const unsigned short* srcp = W2T + c * 512 + step * 32;
#pragma unroll
      for (int q = 0; q < 4; ++q) {
        bf16x8 w = *(const bf16x8*)(srcp + q * 8);
        *(bf16x8*)(sm + 49152 + c * 64 + ((q ^ ((c >> 1) & 3)) * 16)) = w;
      }
    }
    __syncthreads();
    const int arow = 16 * wr + (lane & 15);
    const int aslot = step * 4 + (lane >> 4);
    const bf16x8 af = *(const bf16x8*)(sm + 16384 + arow * 1024 + ((aslot ^ (arow & 7)) * 16));
#pragma unroll
    for (int ct = 0; ct < 8; ++ct) {
      const int c = 128 * wc + 16 * ct + (lane & 15);
      const bf16x8 bfr =
          *(const bf16x8*)(sm + 49152 + c * 64 + ((((lane >> 4)) ^ ((c >> 1) & 3)) * 16));
      acc2[ct] = __builtin_amdgcn_mfma_f32_16x16x32_bf16(af, bfr, acc2[ct], 0, 0, 0);
    }
  }

  const int growbase = r0 + 16 * wr + (lane >> 4) * 4;
  if (growbase < NN) {
#pragma unroll
    for (int ct = 0; ct < 8; ++ct) {
      const int c = 128 * wc + 16 * ct + (lane & 15);
      const float bb = b2[c];
      u16x4 pk;
#pragma unroll
      for (int r = 0; r < 4; ++r) {
        const int grow = growbase + r;
        float v = acc2[ct][r] + bb + vc[(size_t)grow * DIMV + c];
        v = fmaxf(v, 0.f);
        const unsigned short hv = f2bf(v);
        v_rm[(size_t)grow * DIMV + c] = hv;
        pk[r] = hv;
      }
      // vB[ktile][col][kk]: 4 consecutive kk (growbase % 4 == 0, same tile)
      *(u16x4*)(vB + (size_t)(growbase >> 5) * 8192 + c * 32 + (growbase & 31)) = pk;
    }
  }
}

// ---------------------------------------------------------------------------
// K2: Av = A @ v. BM=128, BN=256, BK=32, 512 thr (8 waves: 4 row-grp x 2 col-grp).
// A: coalesced reg-stage -> swizzled fp32 LDS (double-buffered, 1 barrier/step).
// B: dense 1KB fragment loads straight from vB (L2-resident). grid (79, SPLIT).
// ---------------------------------------------------------------------------
__launch_bounds__(512, 4)
__global__ void k_av(const float* __restrict__ A, const unsigned short* __restrict__ vB,
                     float* __restrict__ avp) {
  __shared__ __align__(16) char smA[32768];  // 2 x [128][32] fp32, slot^=(row&7)
  const int t = threadIdx.x, lane = t & 63, wid = t >> 6;
  const int wr = wid >> 1, wc = wid & 1;
  const int r0 = blockIdx.x * 128;
  const int s = blockIdx.y;
  const int kchunk = s * ZCH;
  const int nsteps = (s == SPLIT - 1) ? 40 : 39;
  float* outp = avp + (size_t)s * NN * DIMV;

  // --- staging roles: piece p0 = t (rows 0..63), p1 = 512+t (rows 64..127)
  const int srow0 = t >> 3, sQ = t & 7;
  const int srow1 = 64 + srow0;
  const float* rp0 = A + (size_t)min(r0 + srow0, NN - 1) * NN;
  const float* rp1 = A + (size_t)min(r0 + srow1, NN - 1) * NN;
  const int kq0 = kchunk + sQ * 4;  // + 32*step, clamped to 9996 (B pad makes excess 0)
  const int w0 = srow0 * 128 + ((sQ ^ (srow0 & 7)) * 16);
  const int w1 = srow1 * 128 + ((sQ ^ (srow1 & 7)) * 16);

  // --- A-fragment read offsets (bytes into a buffer)
  int ra00, ra01, ra10, ra11;
  {
    const int q2 = (lane >> 4) * 2;
    int row = wr * 32 + (lane & 15);
    ra00 = row * 128 + (((q2 + 0) ^ (row & 7)) * 16);
    ra01 = row * 128 + (((q2 + 1) ^ (row & 7)) * 16);
    row += 16;
    ra10 = row * 128 + (((q2 + 0) ^ (row & 7)) * 16);
    ra11 = row * 128 + (((q2 + 1) ^ (row & 7)) * 16);
  }

  // --- B pointer: per-lane part constant; advance 8192 u16 (one tile) per step
  const unsigned short* pb =
      vB + (size_t)(s * 39) * 8192 + wc * 4096 + (lane & 15) * 32 + (lane >> 4) * 8;

  f32x4 acc0[8], acc1[8];
#pragma unroll
  for (int i = 0; i < 8; ++i) {
    acc0[i] = (f32x4){0.f, 0.f, 0.f, 0.f};
    acc1[i] = (f32x4){0.f, 0.f, 0.f, 0.f};
  }

#define COMPUTE(BUF, PB)                                                          \
  do {                                                                            \
    const char* abase = smA + (BUF)*16384;                                        \
    const f32x4 a00 = *(const f32x4*)(abase + ra00);                              \
    const f32x4 a01 = *(const f32x4*)(abase + ra01);                              \
    const f32x4 a10 = *(const f32x4*)(abase + ra10);                              \
    const f32x4 a11 = *(const f32x4*)(abase + ra11);                              \
    const bf16x8 af0 = cvt8v(a00, a01);                                           \
    const bf16x8 af1 = cvt8v(a10, a11);                                           \
    _Pragma("unroll") for (int ct = 0; ct < 8; ++ct) {                            \
      const bf16x8 bfr = *(const bf16x8*)((PB) + ct * 512);                       \
      acc0[ct] = __builtin_amdgcn_mfma_f32_16x16x32_bf16(af0, bfr, acc0[ct], 0, 0, 0); \
      acc1[ct] = __builtin_amdgcn_mfma_f32_16x16x32_bf16(af1, bfr, acc1[ct], 0, 0, 0); \
    }                                                                             \
  } while (0)

  // prologue: stage tile 0 into buf 0
  {
    const int kq = min(kq0, 9996);
    const float4 n0 = *(const float4*)(rp0 + kq);
    const float4 n1 = *(const float4*)(rp1 + kq);
    *(float4*)(smA + w0) = n0;
    *(float4*)(smA + w1) = n1;
  }
  __syncthreads();

  int cur = 0;
  for (int st = 0; st < nsteps - 1; ++st) {
    const int kq = min(kq0 + (st + 1) * 32, 9996);
    const float4 n0 = *(const float4*)(rp0 + kq);   // issue early (T14)
    const float4 n1 = *(const float4*)(rp1 + kq);
    COMPUTE(cur, pb);
    char* wb = smA + (cur ^ 1) * 16384;
    *(float4*)(wb + w0) = n0;                        // write late
    *(float4*)(wb + w1) = n1;
    __syncthreads();
    cur ^= 1;
    pb += 8192;
  }
  COMPUTE(cur, pb);
#undef COMPUTE

  // epilogue: store partials
  {
    const int gb = r0 + wr * 32 + (lane >> 4) * 4;
    if (gb < NN) {
#pragma unroll
      for (int ct = 0; ct < 8; ++ct) {
        const int col = wc * 128 + ct * 16 + (lane & 15);
#pragma unroll
        for (int r = 0; r < 4; ++r) outp[(size_t)(gb + r) * DIMV + col] = acc0[ct][r];
      }
    }
    const int gb1 = gb + 16;
    if (gb1 < NN) {
#pragma unroll
      for (int ct = 0; ct < 8; ++ct) {
        const int col = wc * 128 + ct * 16 + (lane & 15);
#pragma unroll
        for (int r = 0; r < 4; ++r) outp[(size_t)(gb1 + r) * DIMV + col] = acc1[ct][r];
      }
    }
  }
}

// ---------------------------------------------------------------------------
// K3: v2 = relu(v@Wl1+bl1) + relu((sum_p avp[p])@Wl2+bl2); writes v2 and d_out
// ---------------------------------------------------------------------------
__launch_bounds__(256, 2)
__global__ void k_out(const unsigned short* __restrict__ v_rm, const float* __restrict__ avp,
                      const unsigned short* __restrict__ Wl1T, const float* __restrict__ bl1,
                      const unsigned short* __restrict__ Wl2T, const float* __restrict__ bl2,
                      float* __restrict__ v2, float* __restrict__ outb, int S) {
  __shared__ __align__(16) char sm[65536];
  const int t = threadIdx.x, lane = t & 63, wid = t >> 6;
  const int wr = wid & 1, wc = wid >> 1;
  const int r0 = blockIdx.x * 32;

  {
    const int row = t >> 3, grow = r0 + row;
#pragma unroll
    for (int q = 0; q < 4; ++q) {
      const int slot = (t & 7) * 4 + q;
      bf16x8 w = (grow < NN) ? *(const bf16x8*)(v_rm + (size_t)grow * DIMV + slot * 8) : bzero8();
      *(bf16x8*)(sm + row * 512 + ((slot ^ (row & 7)) * 16)) = w;
    }
#pragma unroll
    for (int q = 0; q < 4; ++q) {
      const int slot = (t & 7) * 4 + q;
      float buf[8] = {0.f, 0.f, 0.f, 0.f, 0.f, 0.f, 0.f, 0.f};
      if (grow < NN) {
        for (int p = 0; p < S; ++p) {
          const float* pp = avp + (size_t)p * NN * DIMV + (size_t)grow * DIMV + slot * 8;
          const float4 a0 = *(const float4*)pp, a1 = *(const float4*)(pp + 4);
          buf[0] += a0.x; buf[1] += a0.y; buf[2] += a0.z; buf[3] += a0.w;
          buf[4] += a1.x; buf[5] += a1.y; buf[6] += a1.z; buf[7] += a1.w;
        }
      }
      *(bf16x8*)(sm + 16384 + row * 512 + ((slot ^ (row & 7)) * 16)) = pack8(buf);
    }
  }

  f32x4 acc1[8], acc2[8];
#pragma unroll
  for (int i = 0; i < 8; ++i) {
    acc1[i] = (f32x4){0.f, 0.f, 0.f, 0.f};
    acc2[i] = (f32x4){0.f, 0.f, 0.f, 0.f};
  }

  for (int step = 0; step < 8; ++step) {
    __syncthreads();
    {
      const int c = t;
      const unsigned short* s1 = Wl1T + c * 256 + step * 32;
      const unsigned short* s2 = Wl2T + c * 256 + step * 32;
#pragma unroll
      for (int q = 0; q < 4; ++q) {
        const int ps = (q ^ ((c >> 1) & 3)) * 16;
        *(bf16x8*)(sm + 32768 + c * 64 + ps) = *(const bf16x8*)(s1 + q * 8);
        *(bf16x8*)(sm + 49152 + c * 64 + ps) = *(const bf16x8*)(s2 + q * 8);
      }
    }
    __syncthreads();
    const int arow = 16 * wr + (lane & 15);
    const int aslot = step * 4 + (lane >> 4);
    const bf16x8 a1 = *(const bf16x8*)(sm + arow * 512 + ((aslot ^ (arow & 7)) * 16));
    const bf16x8 a2 = *(const bf16x8*)(sm + 16384 + arow * 512 + ((aslot ^ (arow & 7)) * 16));
#pragma unroll
    for (int ct = 0; ct < 8; ++ct) {
      const int c = 128 * wc + 16 * ct + (lane & 15);
      const int bs = (((lane >> 4)) ^ ((c >> 1) & 3)) * 16;
      acc1[ct] = __builtin_amdgcn_mfma_f32_16x16x32_bf16(
          a1, *(const bf16x8*)(sm + 32768 + c * 64 + bs), acc1[ct], 0, 0, 0);
      acc2[ct] = __builtin_amdgcn_mfma_f32_16x16x32_bf16(
          a2, *(const bf16x8*)(sm + 49152 + c * 64 + bs), acc2[ct], 0, 0, 0);
    }
  }

  const int growbase = r0 + 16 * wr + (lane >> 4) * 4;
  if (growbase < NN) {
#pragma unroll
    for (int ct = 0; ct < 8; ++ct) {
      const int c = 128 * wc + 16 * ct + (lane & 15);
      const float u1 = bl1[c], u2 = bl2[c];
#pragma unroll
      for (int r = 0; r < 4; ++r) {
        const float x = fmaxf(acc1[ct][r] + u1, 0.f) + fmaxf(acc2[ct][r] + u2, 0.f);
        v2[(size_t)(growbase + r) * DIMV + c] = x;
        outb[(size_t)(growbase + r) * DIMV + c] = x;
      }
    }
  }
}

// ---------------------------------------------------------------------------
// K4a: histogram of dst
// ---------------------------------------------------------------------------
__global__ void k_hist(const int* __restrict__ dst, int* __restrict__ counts) {
  const int e = blockIdx.x * 256 + threadIdx.x;
  if (e < NEDGE) atomicAdd(&counts[dst[e]], 1);
}

// ---------------------------------------------------------------------------
// K4b: exclusive scan of counts[10000] -> offsets[10001], cursor copy
// ---------------------------------------------------------------------------
__global__ void k_scan(const int* __restrict__ counts, int* __restrict__ offsets,
                       int* __restrict__ cursor) {
  __shared__ int sm[1024];
  __shared__ int carry;
  const int t = threadIdx.x;
  if (t == 0) carry = 0;
  __syncthreads();
  for (int base = 0; base < NN; base += 1024) {
    const int i = base + t;
    const int x = (i < NN) ? counts[i] : 0;
    sm[t] = x;
    __syncthreads();
    for (int off = 1; off < 1024; off <<= 1) {
      int y = (t >= off) ? sm[t - off] : 0;
      __syncthreads();
      sm[t] += y;
      __syncthreads();
    }
    const int excl = sm[t] - x + carry;
    if (i < NN) { offsets[i] = excl; cursor[i] = excl; }
    __syncthreads();
    if (t == 1023) carry += sm[1023];
    __syncthreads();
  }
  if (t == 0) offsets[NN] = carry;
}

// ---------------------------------------------------------------------------
// K4c: fill buckets with src ids
// ---------------------------------------------------------------------------
__global__ void k_fill(const int* __restrict__ src, const int* __restrict__ dst,
                       int* __restrict__ cursor, int* __restrict__ srcbuf) {
  const int e = blockIdx.x * 256 + threadIdx.x;
  if (e < NEDGE) {
    const int pos = atomicAdd(&cursor[dst[e]], 1);
    srcbuf[pos] = src[e];
  }
}

// ---------------------------------------------------------------------------
// K4d: gather-sum, one wave per dst node, 4-deep unrolled.
// ---------------------------------------------------------------------------
__launch_bounds__(256)
__global__ void k_gather(const float* __restrict__ v2, const int* __restrict__ offsets,
                         const int* __restrict__ srcbuf, float* __restrict__ outb) {
  const int n = (blockIdx.x * 256 + threadIdx.x) >> 6;
  if (n >= NN) return;
  const int lane = threadIdx.x & 63;
  const int beg = offsets[n], end = offsets[n + 1];
  float4 a0 = {0.f, 0.f, 0.f, 0.f}, a1 = a0, a2 = a0, a3 = a0;
  int j = beg;
  for (; j + 4 <= end; j += 4) {
    const int s0 = srcbuf[j], s1 = srcbuf[j + 1], s2 = srcbuf[j + 2], s3 = srcbuf[j + 3];
    const float4 x0 = *(const float4*)(v2 + (size_t)s0 * DIMV + lane * 4);
    const float4 x1 = *(const float4*)(v2 + (size_t)s1 * DIMV + lane * 4);
    const float4 x2 = *(const float4*)(v2 + (size_t)s2 * DIMV + lane * 4);
    const float4 x3 = *(const float4*)(v2 + (size_t)s3 * DIMV + lane * 4);
    a0.x += x0.x; a0.y += x0.y; a0.z += x0.z; a0.w += x0.w;
    a1.x += x1.x; a1.y += x1.y; a1.z += x1.z; a1.w += x1.w;
    a2.x += x2.x; a2.y += x2.y; a2.z += x2.z; a2.w += x2.w;
    a3.x += x3.x; a3.y += x3.y; a3.z += x3.z; a3.w += x3.w;
  }
  for (; j < end; ++j) {
    const int s0 = srcbuf[j];
    const float4 x0 = *(const float4*)(v2 + (size_t)s0 * DIMV + lane * 4);
    a0.x += x0.x; a0.y += x0.y; a0.z += x0.z; a0.w += x0.w;
  }
  a0.x += a1.x + a2.x + a3.x; a0.y += a1.y + a2.y + a3.y;
  a0.z += a1.z + a2.z + a3.z; a0.w += a1.w + a2.w + a3.w;
  float* o = outb + (size_t)n * DIMV + lane * 4;
  float4 cur = *(const float4*)o;
  cur.x += a0.x; cur.y += a0.y; cur.z += a0.z; cur.w += a0.w;
  *(float4*)o = cur;
}

// ---------------------------------------------------------------------------
extern "C" void kernel_launch(void* const* d_in, const int* in_sizes, int n_in,
                              void* d_out, int out_size, void* d_ws, size_t ws_size,
                              hipStream_t stream) {
  const float* vc  = (const float*)d_in[0];
  const float* A   = (const float*)d_in[1];
  const int*   src = (const int*)d_in[2];
  const int*   dst = (const int*)d_in[3];
  const float* W1  = (const float*)d_in[4];
  const float* b1  = (const float*)d_in[5];
  const float* W2  = (const float*)d_in[6];
  const float* b2  = (const float*)d_in[7];
  const float* Wl1 = (const float*)d_in[8];
  const float* bl1 = (const float*)d_in[9];
  const float* Wl2 = (const float*)d_in[10];
  const float* bl2 = (const float*)d_in[11];
  float* outb = (float*)d_out;
  char* ws = (char*)d_ws;

  // carve (bytes):
  unsigned short* W1T  = (unsigned short*)(ws + 0);          // 512x256 bf16
  unsigned short* W2T  = (unsigned short*)(ws + 262144);     // 256x512
  unsigned short* Wl1T = (unsigned short*)(ws + 524288);     // 256x256
  unsigned short* Wl2T = (unsigned short*)(ws + 655360);     // 256x256
  unsigned short* vB   = (unsigned short*)(ws + 786432);     // [313][256][32] bf16, 5.13 MB
  unsigned short* v_rm = (unsigned short*)(ws + 5914624);    // [10000][256] bf16
  float*          avp  = (float*)(ws + 11034624);            // SPLIT x [10000][256] f32 (82 MB)
  float*          v2   = avp;  // aliases partial 0: k_out reads its rows before writing them

  // CSR arrays alias the vB region (only used after k_av has consumed vB)
  int* counts  = (int*)(ws + 786432);
  int* offsets = (int*)(ws + 829440);
  int* cursor  = (int*)(ws + 872448);
  int* srcbuf  = (int*)(ws + 915456);

  hipLaunchKernelGGL(k_conv, dim3(512), dim3(256), 0, stream,
                     W1, W2, Wl1, Wl2, W1T, W2T, Wl1T, Wl2T, vB);
  hipLaunchKernelGGL(k_mlp, dim3(313), dim3(256), 0, stream,
                     vc, W1T, b1, W2T, b2, v_rm, vB);
  hipLaunchKernelGGL(k_av, dim3(79, SPLIT), dim3(512), 0, stream, A, vB, avp);

  // CSR build (vB is dead from here on)
  hipMemsetAsync(counts, 0, NN * sizeof(int), stream);
  hipLaunchKernelGGL(k_hist, dim3((NEDGE + 255) / 256), dim3(256), 0, stream, dst, counts);
  hipLaunchKernelGGL(k_scan, dim3(1), dim3(1024), 0, stream, counts, offsets, cursor);
  hipLaunchKernelGGL(k_fill, dim3((NEDGE + 255) / 256), dim3(256), 0, stream,
                     src, dst, cursor, srcbuf);

  hipLaunchKernelGGL(k_out, dim3(313), dim3(256), 0, stream,
                     v_rm, avp, Wl1T, bl1, Wl2T, bl2, v2, outb, SPLIT);
  hipLaunchKernelGGL(k_gather, dim3((NN * 64 + 255) / 256), dim3(256), 0, stream,
                     v2, offsets, srcbuf, outb);
}

// Round 6
// 324.396 us; speedup vs baseline: 1.8858x; 1.3580x over previous
//
#include <hip/hip_runtime.h>
#include <stdint.h>

#define NN 10000
#define DIMV 256
#define HID 512
#define NEDGE 320000
#define SPLIT 6
#define KCH 1664      // k per chunk (52 tiles); chunk 5: 1680 (52 tiles + tail tile 312)
#define NKT 313       // total 32-k tiles (tile 312 zero-padded above k=10000)

typedef __attribute__((ext_vector_type(8))) short bf16x8;
typedef __attribute__((ext_vector_type(4))) float f32x4;
typedef __attribute__((ext_vector_type(4))) unsigned short u16x4;

__device__ __forceinline__ unsigned short f2bf(float f) {
  union { float f; unsigned int u; } c; c.f = f;
  return (unsigned short)((c.u + 0x7FFFu + ((c.u >> 16) & 1u)) >> 16);
}

__device__ __forceinline__ bf16x8 bzero8() {
  bf16x8 r;
#pragma unroll
  for (int i = 0; i < 8; ++i) r[i] = 0;
  return r;
}

__device__ __forceinline__ bf16x8 pack8(const float* x) {
  bf16x8 r;
#pragma unroll
  for (int i = 0; i < 8; ++i) r[i] = (short)f2bf(x[i]);
  return r;
}

// two f32x4 -> bf16x8 via v_cvt_pk_bf16_f32 (RNE, matches f2bf)
__device__ __forceinline__ bf16x8 cvt8v(const f32x4 a, const f32x4 b) {
  union { unsigned int u[4]; bf16x8 v; } r;
  asm("v_cvt_pk_bf16_f32 %0, %1, %2" : "=v"(r.u[0]) : "v"(a[0]), "v"(a[1]));
  asm("v_cvt_pk_bf16_f32 %0, %1, %2" : "=v"(r.u[1]) : "v"(a[2]), "v"(a[3]));
  asm("v_cvt_pk_bf16_f32 %0, %1, %2" : "=v"(r.u[2]) : "v"(b[0]), "v"(b[1]));
  asm("v_cvt_pk_bf16_f32 %0, %1, %2" : "=v"(r.u[3]) : "v"(b[2]), "v"(b[3]));
  return r.v;
}

// async global->LDS, 16B per lane; dest = wave-uniform base + lane*16
typedef __attribute__((address_space(1))) unsigned int gu32;
typedef __attribute__((address_space(3))) unsigned int lu32;
__device__ __forceinline__ void glds16(const void* g, void* l) {
  __builtin_amdgcn_global_load_lds((const gu32*)g, (lu32*)l, 16, 0, 0);
}

// vB tile byte swizzle: within tile, byte(col,kk) = col*64 + ((g ^ ((col>>1)&3))<<4) + (kk&7)*2
// where g = kk>>3. Written swizzled by k_mlp/k_conv; k_av reads with same XOR.

// ---------------------------------------------------------------------------
// K0: weights fp32 -> bf16 transposed; zero vB's k-pad (tile 312, kk 16..31)
// ---------------------------------------------------------------------------
__global__ void k_conv(const float* __restrict__ W1, const float* __restrict__ W2,
                       const float* __restrict__ Wl1, const float* __restrict__ Wl2,
                       unsigned short* __restrict__ W1T, unsigned short* __restrict__ W2T,
                       unsigned short* __restrict__ Wl1T, unsigned short* __restrict__ Wl2T,
                       unsigned short* __restrict__ vB) {
  int i = blockIdx.x * 256 + threadIdx.x;
  if (i < 131072) {
    { int k = i >> 9, o = i & 511; W1T[o * 256 + k] = f2bf(W1[i]); }
    { int k = i >> 8, o = i & 255; W2T[o * 512 + k] = f2bf(W2[i]); }
    if (i < 65536) {
      int k = i >> 8, o = i & 255;
      Wl1T[o * 256 + k] = f2bf(Wl1[i]);
      Wl2T[o * 256 + k] = f2bf(Wl2[i]);
    }
    if (i < 4096) {  // zero vB tile 312, kk in [16,32), swizzled address
      int c = i >> 4, kk = 16 + (i & 15);
      int g = kk >> 3;
      int byte = c * 64 + ((g ^ ((c >> 1) & 3)) << 4) + (kk & 7) * 2;
      *(unsigned short*)((char*)vB + (size_t)312 * 16384 + byte) = 0;
    }
  }
}

// ---------------------------------------------------------------------------
// K1: v = relu(vc + relu(vc@W1+b1)@W2 + b2) -> v_rm [N][256] and
//     vB [313 tiles][256 cols][32 k] bf16, byte-swizzled (B of A@v)
// ---------------------------------------------------------------------------
__launch_bounds__(256, 2)
__global__ void k_mlp(const float* __restrict__ vc,
                      const unsigned short* __restrict__ W1T, const float* __restrict__ b1,
                      const unsigned short* __restrict__ W2T, const float* __restrict__ b2,
                      unsigned short* __restrict__ v_rm, unsigned short* __restrict__ vB) {
  __shared__ __align__(16) char sm[65536];
  const int t = threadIdx.x;
  const int lane = t & 63, wid = t >> 6;
  const int wr = wid & 1, wc = wid >> 1;
  const int r0 = blockIdx.x * 32;

  {  // stage vc tile -> bf16
    const int row = t >> 3, grow = r0 + row;
#pragma unroll
    for (int q = 0; q < 4; ++q) {
      const int slot = (t & 7) * 4 + q;
      float buf[8] = {0.f, 0.f, 0.f, 0.f, 0.f, 0.f, 0.f, 0.f};
      if (grow < NN) {
        const float4 x0 = *(const float4*)(vc + (size_t)grow * DIMV + slot * 8);
        const float4 x1 = *(const float4*)(vc + (size_t)grow * DIMV + slot * 8 + 4);
        buf[0] = x0.x; buf[1] = x0.y; buf[2] = x0.z; buf[3] = x0.w;
        buf[4] = x1.x; buf[5] = x1.y; buf[6] = x1.z; buf[7] = x1.w;
      }
      *(bf16x8*)(sm + row * 512 + ((slot ^ (row & 7)) * 16)) = pack8(buf);
    }
  }

  f32x4 acc1[16];
#pragma unroll
  for (int i = 0; i < 16; ++i) acc1[i] = (f32x4){0.f, 0.f, 0.f, 0.f};

  for (int step = 0; step < 8; ++step) {
    __syncthreads();
#pragma unroll
    for (int rr = 0; rr < 2; ++rr) {
      const int c = t + rr * 256;
      const unsigned short* srcp = W1T + c * 256 + step * 32;
#pragma unroll
      for (int q = 0; q < 4; ++q) {
        bf16x8 w = *(const bf16x8*)(srcp + q * 8);
        *(bf16x8*)(sm + 16384 + c * 64 + ((q ^ ((c >> 1) & 3)) * 16)) = w;
      }
    }
    __syncthreads();
    const int arow = 16 * wr + (lane & 15);
    const int aslot = step * 4 + (lane >> 4);
    const bf16x8 af = *(const bf16x8*)(sm + arow * 512 + ((aslot ^ (arow & 7)) * 16));
#pragma unroll
    for (int ct = 0; ct < 16; ++ct) {
      const int c = 256 * wc + 16 * ct + (lane & 15);
      const bf16x8 bfr =
          *(const bf16x8*)(sm + 16384 + c * 64 + ((((lane >> 4)) ^ ((c >> 1) & 3)) * 16));
      acc1[ct] = __builtin_amdgcn_mfma_f32_16x16x32_bf16(af, bfr, acc1[ct], 0, 0, 0);
    }
  }
  __syncthreads();
#pragma unroll
  for (int ct = 0; ct < 16; ++ct) {
    const int c = 256 * wc + 16 * ct + (lane & 15);
    const float bb = b1[c];
#pragma unroll
    for (int r = 0; r < 4; ++r) {
      const int row = 16 * wr + (lane >> 4) * 4 + r;
      float v = fmaxf(acc1[ct][r] + bb, 0.f);
      const int slot = c >> 3;
      *(unsigned short*)(sm + 16384 + row * 1024 + ((slot ^ (row & 7)) * 16) + (c & 7) * 2) =
          f2bf(v);
    }
  }

  f32x4 acc2[8];
#pragma unroll
  for (int i = 0; i < 8; ++i) acc2[i] = (f32x4){0.f, 0.f, 0.f, 0.f};

  for (int step = 0; step < 16; ++step) {
    __syncthreads();
    {
      const int c = t;
      const unsigned short* srcp = W2T + c * 512 + step * 32;
#pragma unroll
      for (int q = 0; q < 4; ++q) {
        bf16x8 w = *(const bf16x8*)(srcp + q * 8);
        *(bf16x8*)(sm + 49152 + c * 64 + ((q ^ ((c >> 1) & 3)) * 16)) = w;
      }
    }
    __syncthreads();
    const int arow = 16 * wr + (lane & 15);
    const int aslot = step * 4 + (lane >> 4);
    const bf16x8 af = *(const bf16x8*)(sm + 16384 + arow * 1024 + ((aslot ^ (arow & 7)) * 16));
#pragma unroll
    for (int ct = 0; ct < 8; ++ct) {
      const int c = 128 * wc + 16 * ct + (lane & 15);
      const bf16x8 bfr =
          *(const bf16x8*)(sm + 49152 + c * 64 + ((((lane >> 4)) ^ ((c >> 1) & 3)) * 16));
      acc2[ct] = __builtin_amdgcn_mfma_f32_16x16x32_bf16(af, bfr, acc2[ct], 0, 0, 0);
    }
  }

  const int growbase = r0 + 16 * wr + (lane >> 4) * 4;
  if (growbase < NN) {
#pragma unroll
    for (int ct = 0; ct < 8; ++ct) {
      const int c = 128 * wc + 16 * ct + (lane & 15);
      const float bb = b2[c];
      u16x4 pk;
#pragma unroll
      for (int r = 0; r < 4; ++r) {
        const int grow = growbase + r;
        float v = acc2[ct][r] + bb + vc[(size_t)grow * DIMV + c];
        v = fmaxf(v, 0.f);
        const unsigned short hv = f2bf(v);
        v_rm[(size_t)grow * DIMV + c] = hv;
        pk[r] = hv;
      }
      // swizzled vB write: tile = growbase>>5, kk0 = growbase&31 (mult of 4)
      const int tile = growbase >> 5, kk0 = growbase & 31;
      const int g = kk0 >> 3;
      const int byte = c * 64 + ((g ^ ((c >> 1) & 3)) << 4) + (kk0 & 7) * 2;
      *(u16x4*)((char*)vB + (size_t)tile * 16384 + byte) = pk;
    }
  }
}

// ---------------------------------------------------------------------------
// K2: Av = A @ v.  BM=256, BN=256, BK=32, 512 thr (8 waves: 4 wr x 2 wc).
// A: reg-stage -> XOR-swizzled fp32 LDS (dbuf). B: global_load_lds from
// pre-swizzled vB (dbuf, linear dest). 1 barrier/step. grid 240 (XCD-chunked).
// ---------------------------------------------------------------------------
__launch_bounds__(512, 2)
__global__ void k_av(const float* __restrict__ A, const unsigned short* __restrict__ vB,
                     float* __restrict__ avp) {
  __shared__ __align__(16) char sm[98304];  // A: 2x32KB @0; B: 2x16KB @65536
  const int t = threadIdx.x, lane = t & 63, wid = t >> 6;
  const int wr = wid >> 1, wc = wid & 1;

  // XCD-chunked remap of 240 blocks: xcd k gets g in [k*30, k*30+30)
  const int f = blockIdx.x;
  const int g = (f & 7) * 30 + (f >> 3);
  const int s = g / 40;          // k-chunk 0..5
  const int xb = g - s * 40;     // row-block 0..39
  const int r0 = xb * 256;
  const int kbase = s * KCH;
  const int tile0 = s * 52;
  const int nst = (s == SPLIT - 1) ? 53 : 52;
  float* outp = avp + (size_t)s * NN * DIMV;

  // --- A staging roles: 4 pieces; piece p: row = p*64 + (t>>3), 16B chunk sQ = t&7
  const int srow = t >> 3, sQ = t & 7;
  const int sQ4 = sQ * 4;
  const float* ap0 = A + (size_t)min(r0 + srow, NN - 1) * NN;
  const float* ap1 = A + (size_t)min(r0 + 64 + srow, NN - 1) * NN;
  const float* ap2 = A + (size_t)min(r0 + 128 + srow, NN - 1) * NN;
  const float* ap3 = A + (size_t)min(r0 + 192 + srow, NN - 1) * NN;
  const int wof = ((sQ ^ (srow & 7)) << 4);
  const int w0 = (srow)*128 + wof;
  const int w1 = (64 + srow) * 128 + wof;
  const int w2 = (128 + srow) * 128 + wof;
  const int w3 = (192 + srow) * 128 + wof;

  f32x4 aR0, aR1, aR2, aR3;

#define AISSUE(ST)                                           \
  do {                                                       \
    int kq = kbase + (ST)*32 + sQ4;                          \
    kq = min(kq, 9996); /* overshoot hits B pad zeros */     \
    aR0 = *(const f32x4*)(ap0 + kq);                         \
    aR1 = *(const f32x4*)(ap1 + kq);                         \
    aR2 = *(const f32x4*)(ap2 + kq);                         \
    aR3 = *(const f32x4*)(ap3 + kq);                         \
  } while (0)

#define AWRITE(BUF)                                          \
  do {                                                       \
    char* wb = sm + (BUF)*32768;                             \
    *(f32x4*)(wb + w0) = aR0;                                \
    *(f32x4*)(wb + w1) = aR1;                                \
    *(f32x4*)(wb + w2) = aR2;                                \
    *(f32x4*)(wb + w3) = aR3;                                \
  } while (0)

#define BSTAGE(BUF, TILE)                                                     \
  do {                                                                        \
    char* lb = sm + 65536 + (BUF)*16384 + wid * 1024;                         \
    const char* gb_ = (const char*)vB + (size_t)(TILE)*16384 + wid * 1024 +   \
                      lane * 16;                                              \
    glds16(gb_, lb);                                                          \
    glds16(gb_ + 8192, lb + 8192);                                            \
  } while (0)

  f32x4 acc0[8], acc1[8], acc2[8], acc3[8];
#pragma unroll
  for (int i = 0; i < 8; ++i) {
    acc0[i] = (f32x4){0.f, 0.f, 0.f, 0.f};
    acc1[i] = (f32x4){0.f, 0.f, 0.f, 0.f};
    acc2[i] = (f32x4){0.f, 0.f, 0.f, 0.f};
    acc3[i] = (f32x4){0.f, 0.f, 0.f, 0.f};
  }

#define COMPUTE(CUR)                                                               \
  do {                                                                             \
    const char* ab = sm + (CUR)*32768;                                             \
    const char* bb = sm + 65536 + (CUR)*16384;                                     \
    const int q2 = (lane >> 4) * 2;                                                \
    bf16x8 af0, af1, af2, af3;                                                     \
    {                                                                              \
      int row = wr * 64 + (lane & 15);                                             \
      af0 = cvt8v(*(const f32x4*)(ab + row * 128 + (((q2) ^ (row & 7)) << 4)),     \
                  *(const f32x4*)(ab + row * 128 + (((q2 + 1) ^ (row & 7)) << 4)));\
      row += 16;                                                                   \
      af1 = cvt8v(*(const f32x4*)(ab + row * 128 + (((q2) ^ (row & 7)) << 4)),     \
                  *(const f32x4*)(ab + row * 128 + (((q2 + 1) ^ (row & 7)) << 4)));\
      row += 16;                                                                   \
      af2 = cvt8v(*(const f32x4*)(ab + row * 128 + (((q2) ^ (row & 7)) << 4)),     \
                  *(const f32x4*)(ab + row * 128 + (((q2 + 1) ^ (row & 7)) << 4)));\
      row += 16;                                                                   \
      af3 = cvt8v(*(const f32x4*)(ab + row * 128 + (((q2) ^ (row & 7)) << 4)),     \
                  *(const f32x4*)(ab + row * 128 + (((q2 + 1) ^ (row & 7)) << 4)));\
    }                                                                              \
    _Pragma("unroll") for (int ct = 0; ct < 8; ++ct) {                             \
      const int col = wc * 128 + ct * 16 + (lane & 15);                            \
      const bf16x8 bfr = *(const bf16x8*)(                                         \
          bb + col * 64 + (((lane >> 4) ^ ((col >> 1) & 3)) << 4));                \
      acc0[ct] = __builtin_amdgcn_mfma_f32_16x16x32_bf16(af0, bfr, acc0[ct], 0, 0, 0); \
      acc1[ct] = __builtin_amdgcn_mfma_f32_16x16x32_bf16(af1, bfr, acc1[ct], 0, 0, 0); \
      acc2[ct] = __builtin_amdgcn_mfma_f32_16x16x32_bf16(af2, bfr, acc2[ct], 0, 0, 0); \
      acc3[ct] = __builtin_amdgcn_mfma_f32_16x16x32_bf16(af3, bfr, acc3[ct], 0, 0, 0); \
    }                                                                              \
  } while (0)

  // prologue: stage tile 0 into buf 0
  AISSUE(0);
  AWRITE(0);
  BSTAGE(0, tile0);
  __syncthreads();

  int cur = 0;
  for (int st = 0; st < nst; ++st) {
    const bool more = (st + 1 < nst);
    if (more) {
      AISSUE(st + 1);            // issue next A loads (regs)
      BSTAGE(cur ^ 1, tile0 + st + 1);  // issue next B glds
    }
    COMPUTE(cur);
    if (more) AWRITE(cur ^ 1);   // vmcnt lands here (after MFMA cluster)
    __syncthreads();             // compiler drains vmcnt+lgkmcnt before barrier
    cur ^= 1;
  }
#undef AISSUE
#undef AWRITE
#undef BSTAGE
#undef COMPUTE

  // epilogue: store partials
#define STORE(ACC, RI)                                                        \
  do {                                                                        \
    const int gb = r0 + wr * 64 + (RI)*16 + (lane >> 4) * 4;                  \
    if (gb < NN) {                                                            \
      _Pragma("unroll") for (int ct = 0; ct < 8; ++ct) {                      \
        const int col = wc * 128 + ct * 16 + (lane & 15);                     \
        outp[(size_t)(gb + 0) * DIMV + col] = ACC[ct][0];                     \
        outp[(size_t)(gb + 1) * DIMV + col] = ACC[ct][1];                     \
        outp[(size_t)(gb + 2) * DIMV + col] = ACC[ct][2];                     \
        outp[(size_t)(gb + 3) * DIMV + col] = ACC[ct][3];                     \
      }                                                                       \
    }                                                                         \
  } while (0)
  STORE(acc0, 0);
  STORE(acc1, 1);
  STORE(acc2, 2);
  STORE(acc3, 3);
#undef STORE
}

// ---------------------------------------------------------------------------
// K3: v2 = relu(v@Wl1+bl1) + relu((sum_p avp[p])@Wl2+bl2); writes v2 and d_out
// ---------------------------------------------------------------------------
__launch_bounds__(256, 2)
__global__ void k_out(const unsigned short* __restrict__ v_rm, const float* __restrict__ avp,
                      const unsigned short* __restrict__ Wl1T, const float* __restrict__ bl1,
                      const unsigned short* __restrict__ Wl2T, const float* __restrict__ bl2,
                      float* __restrict__ v2, float* __restrict__ outb, int S) {
  __shared__ __align__(16) char sm[65536];
  const int t = threadIdx.x, lane = t & 63, wid = t >> 6;
  const int wr = wid & 1, wc = wid >> 1;
  const int r0 = blockIdx.x * 32;

  {
    const int row = t >> 3, grow = r0 + row;
#pragma unroll
    for (int q = 0; q < 4; ++q) {
      const int slot = (t & 7) * 4 + q;
      bf16x8 w = (grow < NN) ? *(const bf16x8*)(v_rm + (size_t)grow * DIMV + slot * 8) : bzero8();
      *(bf16x8*)(sm + row * 512 + ((slot ^ (row & 7)) * 16)) = w;
    }
#pragma unroll
    for (int q = 0; q < 4; ++q) {
      const int slot = (t & 7) * 4 + q;
      float buf[8] = {0.f, 0.f, 0.f, 0.f, 0.f, 0.f, 0.f, 0.f};
      if (grow < NN) {
        for (int p = 0; p < S; ++p) {
          const float* pp = avp + (size_t)p * NN * DIMV + (size_t)grow * DIMV + slot * 8;
          const float4 a0 = *(const float4*)pp, a1 = *(const float4*)(pp + 4);
          buf[0] += a0.x; buf[1] += a0.y; buf[2] += a0.z; buf[3] += a0.w;
          buf[4] += a1.x; buf[5] += a1.y; buf[6] += a1.z; buf[7] += a1.w;
        }
      }
      *(bf16x8*)(sm + 16384 + row * 512 + ((slot ^ (row & 7)) * 16)) = pack8(buf);
    }
  }

  f32x4 acc1[8], acc2[8];
#pragma unroll
  for (int i = 0; i < 8; ++i) {
    acc1[i] = (f32x4){0.f, 0.f, 0.f, 0.f};
    acc2[i] = (f32x4){0.f, 0.f, 0.f, 0.f};
  }

  for (int step = 0; step < 8; ++step) {
    __syncthreads();
    {
      const int c = t;
      const unsigned short* s1 = Wl1T + c * 256 + step * 32;
      const unsigned short* s2 = Wl2T + c * 256 + step * 32;
#pragma unroll
      for (int q = 0; q < 4; ++q) {
        const int ps = (q ^ ((c >> 1) & 3)) * 16;
        *(bf16x8*)(sm + 32768 + c * 64 + ps) = *(const bf16x8*)(s1 + q * 8);
        *(bf16x8*)(sm + 49152 + c * 64 + ps) = *(const bf16x8*)(s2 + q * 8);
      }
    }
    __syncthreads();
    const int arow = 16 * wr + (lane & 15);
    const int aslot = step * 4 + (lane >> 4);
    const bf16x8 a1 = *(const bf16x8*)(sm + arow * 512 + ((aslot ^ (arow & 7)) * 16));
    const bf16x8 a2 = *(const bf16x8*)(sm + 16384 + arow * 512 + ((aslot ^ (arow & 7)) * 16));
#pragma unroll
    for (int ct = 0; ct < 8; ++ct) {
      const int c = 128 * wc + 16 * ct + (lane & 15);
      const int bs = (((lane >> 4)) ^ ((c >> 1) & 3)) * 16;
      acc1[ct] = __builtin_amdgcn_mfma_f32_16x16x32_bf16(
          a1, *(const bf16x8*)(sm + 32768 + c * 64 + bs), acc1[ct], 0, 0, 0);
      acc2[ct] = __builtin_amdgcn_mfma_f32_16x16x32_bf16(
          a2, *(const bf16x8*)(sm + 49152 + c * 64 + bs), acc2[ct], 0, 0, 0);
    }
  }

  const int growbase = r0 + 16 * wr + (lane >> 4) * 4;
  if (growbase < NN) {
#pragma unroll
    for (int ct = 0; ct < 8; ++ct) {
      const int c = 128 * wc + 16 * ct + (lane & 15);
      const float u1 = bl1[c], u2 = bl2[c];
#pragma unroll
      for (int r = 0; r < 4; ++r) {
        const float x = fmaxf(acc1[ct][r] + u1, 0.f) + fmaxf(acc2[ct][r] + u2, 0.f);
        v2[(size_t)(growbase + r) * DIMV + c] = x;
        outb[(size_t)(growbase + r) * DIMV + c] = x;
      }
    }
  }
}

// ---------------------------------------------------------------------------
__global__ void k_hist(const int* __restrict__ dst, int* __restrict__ counts) {
  const int e = blockIdx.x * 256 + threadIdx.x;
  if (e < NEDGE) atomicAdd(&counts[dst[e]], 1);
}

__global__ void k_scan(const int* __restrict__ counts, int* __restrict__ offsets,
                       int* __restrict__ cursor) {
  __shared__ int sm[1024];
  __shared__ int carry;
  const int t = threadIdx.x;
  if (t == 0) carry = 0;
  __syncthreads();
  for (int base = 0; base < NN; base += 1024) {
    const int i = base + t;
    const int x = (i < NN) ? counts[i] : 0;
    sm[t] = x;
    __syncthreads();
    for (int off = 1; off < 1024; off <<= 1) {
      int y = (t >= off) ? sm[t - off] : 0;
      __syncthreads();
      sm[t] += y;
      __syncthreads();
    }
    const int excl = sm[t] - x + carry;
    if (i < NN) { offsets[i] = excl; cursor[i] = excl; }
    __syncthreads();
    if (t == 1023) carry += sm[1023];
    __syncthreads();
  }
  if (t == 0) offsets[NN] = carry;
}

__global__ void k_fill(const int* __restrict__ src, const int* __restrict__ dst,
                       int* __restrict__ cursor, int* __restrict__ srcbuf) {
  const int e = blockIdx.x * 256 + threadIdx.x;
  if (e < NEDGE) {
    const int pos = atomicAdd(&cursor[dst[e]], 1);
    srcbuf[pos] = src[e];
  }
}

__launch_bounds__(256)
__global__ void k_gather(const float* __restrict__ v2, const int* __restrict__ offsets,
                         const int* __restrict__ srcbuf, float* __restrict__ outb) {
  const int n = (blockIdx.x * 256 + threadIdx.x) >> 6;
  if (n >= NN) return;
  const int lane = threadIdx.x & 63;
  const int beg = offsets[n], end = offsets[n + 1];
  float4 a0 = {0.f, 0.f, 0.f, 0.f}, a1 = a0, a2 = a0, a3 = a0;
  int j = beg;
  for (; j + 4 <= end; j += 4) {
    const int s0 = srcbuf[j], s1 = srcbuf[j + 1], s2 = srcbuf[j + 2], s3 = srcbuf[j + 3];
    const float4 x0 = *(const float4*)(v2 + (size_t)s0 * DIMV + lane * 4);
    const float4 x1 = *(const float4*)(v2 + (size_t)s1 * DIMV + lane * 4);
    const float4 x2 = *(const float4*)(v2 + (size_t)s2 * DIMV + lane * 4);
    const float4 x3 = *(const float4*)(v2 + (size_t)s3 * DIMV + lane * 4);
    a0.x += x0.x; a0.y += x0.y; a0.z += x0.z; a0.w += x0.w;
    a1.x += x1.x; a1.y += x1.y; a1.z += x1.z; a1.w += x1.w;
    a2.x += x2.x; a2.y += x2.y; a2.z += x2.z; a2.w += x2.w;
    a3.x += x3.x; a3.y += x3.y; a3.z += x3.z; a3.w += x3.w;
  }
  for (; j < end; ++j) {
    const int s0 = srcbuf[j];
    const float4 x0 = *(const float4*)(v2 + (size_t)s0 * DIMV + lane * 4);
    a0.x += x0.x; a0.y += x0.y; a0.z += x0.z; a0.w += x0.w;
  }
  a0.x += a1.x + a2.x + a3.x; a0.y += a1.y + a2.y + a3.y;
  a0.z += a1.z + a2.z + a3.z; a0.w += a1.w + a2.w + a3.w;
  float* o = outb + (size_t)n * DIMV + lane * 4;
  float4 cur = *(const float4*)o;
  cur.x += a0.x; cur.y += a0.y; cur.z += a0.z; cur.w += a0.w;
  *(float4*)o = cur;
}

// ---------------------------------------------------------------------------
extern "C" void kernel_launch(void* const* d_in, const int* in_sizes, int n_in,
                              void* d_out, int out_size, void* d_ws, size_t ws_size,
                              hipStream_t stream) {
  const float* vc  = (const float*)d_in[0];
  const float* A   = (const float*)d_in[1];
  const int*   src = (const int*)d_in[2];
  const int*   dst = (const int*)d_in[3];
  const float* W1  = (const float*)d_in[4];
  const float* b1  = (const float*)d_in[5];
  const float* W2  = (const float*)d_in[6];
  const float* b2  = (const float*)d_in[7];
  const float* Wl1 = (const float*)d_in[8];
  const float* bl1 = (const float*)d_in[9];
  const float* Wl2 = (const float*)d_in[10];
  const float* bl2 = (const float*)d_in[11];
  float* outb = (float*)d_out;
  char* ws = (char*)d_ws;

  // carve (bytes):
  unsigned short* W1T  = (unsigned short*)(ws + 0);          // 512x256 bf16
  unsigned short* W2T  = (unsigned short*)(ws + 262144);     // 256x512
  unsigned short* Wl1T = (unsigned short*)(ws + 524288);     // 256x256
  unsigned short* Wl2T = (unsigned short*)(ws + 655360);     // 256x256
  unsigned short* vB   = (unsigned short*)(ws + 786432);     // 313 x 16KB swizzled tiles
  unsigned short* v_rm = (unsigned short*)(ws + 5914624);    // [10000][256] bf16
  float*          avp  = (float*)(ws + 11034624);            // SPLIT x [10000][256] f32 (61 MB)
  float*          v2   = avp;  // aliases partial 0: k_out reads rows before writing them

  // CSR arrays alias the vB region (only used after k_av has consumed vB)
  int* counts  = (int*)(ws + 786432);
  int* offsets = (int*)(ws + 829440);
  int* cursor  = (int*)(ws + 872448);
  int* srcbuf  = (int*)(ws + 915456);

  hipLaunchKernelGGL(k_conv, dim3(512), dim3(256), 0, stream,
                     W1, W2, Wl1, Wl2, W1T, W2T, Wl1T, Wl2T, vB);
  hipLaunchKernelGGL(k_mlp, dim3(313), dim3(256), 0, stream,
                     vc, W1T, b1, W2T, b2, v_rm, vB);
  hipLaunchKernelGGL(k_av, dim3(240), dim3(512), 0, stream, A, vB, avp);

  // CSR build (vB is dead from here on)
  hipMemsetAsync(counts, 0, NN * sizeof(int), stream);
  hipLaunchKernelGGL(k_hist, dim3((NEDGE + 255) / 256), dim3(256), 0, stream, dst, counts);
  hipLaunchKernelGGL(k_scan, dim3(1), dim3(1024), 0, stream, counts, offsets, cursor);
  hipLaunchKernelGGL(k_fill, dim3((NEDGE + 255) / 256), dim3(256), 0, stream,
                     src, dst, cursor, srcbuf);

  hipLaunchKernelGGL(k_out, dim3(313), dim3(256), 0, stream,
                     v_rm, avp, Wl1T, bl1, Wl2T, bl2, v2, outb, SPLIT);
  hipLaunchKernelGGL(k_gather, dim3((NN * 64 + 255) / 256), dim3(256), 0, stream,
                     v2, offsets, srcbuf, outb);
}

// Round 7
// 258.362 us; speedup vs baseline: 2.3678x; 1.2556x over previous
//
#include <hip/hip_runtime.h>
#include <stdint.h>

#define NN 10000
#define DIMV 256
#define HID 512
#define NEDGE 320000
#define SPLIT 6
#define KCH 1664      // k per chunk (52 tiles); chunk 5: 53 tiles incl. zero-pad tile 312
#define NKT 313
#define APL 2112      // A LDS plane stride bytes (128*16 + 64 pad)
#define ABUF 8448     // 4*APL
#define BOFF 16896    // 2*ABUF
#define LDSZ 49664    // BOFF + 2*16384

typedef __attribute__((ext_vector_type(8))) short bf16x8;
typedef __attribute__((ext_vector_type(4))) float f32x4;
typedef __attribute__((ext_vector_type(4))) unsigned short u16x4;
typedef __attribute__((ext_vector_type(2))) unsigned int u32x2;

__device__ __forceinline__ unsigned short f2bf(float f) {
  union { float f; unsigned int u; } c; c.f = f;
  return (unsigned short)((c.u + 0x7FFFu + ((c.u >> 16) & 1u)) >> 16);
}
__device__ __forceinline__ float bf2f(unsigned short h) {
  union { unsigned int u; float f; } c; c.u = ((unsigned int)h) << 16;
  return c.f;
}

__device__ __forceinline__ bf16x8 bzero8() {
  bf16x8 r;
#pragma unroll
  for (int i = 0; i < 8; ++i) r[i] = 0;
  return r;
}

__device__ __forceinline__ bf16x8 pack8(const float* x) {
  bf16x8 r;
#pragma unroll
  for (int i = 0; i < 8; ++i) r[i] = (short)f2bf(x[i]);
  return r;
}

// f32x4 -> 4 packed bf16 (8B) via v_cvt_pk_bf16_f32 (RNE, matches f2bf)
__device__ __forceinline__ u32x2 cvt4v(const f32x4 a) {
  u32x2 r;
  asm("v_cvt_pk_bf16_f32 %0, %1, %2" : "=v"(r[0]) : "v"(a[0]), "v"(a[1]));
  asm("v_cvt_pk_bf16_f32 %0, %1, %2" : "=v"(r[1]) : "v"(a[2]), "v"(a[3]));
  return r;
}

// async global->LDS, 16B/lane; LDS dest = wave-uniform base + lane*16
typedef __attribute__((address_space(1))) unsigned int gu32;
typedef __attribute__((address_space(3))) unsigned int lu32;
__device__ __forceinline__ void glds16(const void* g, void* l) {
  __builtin_amdgcn_global_load_lds((const gu32*)g, (lu32*)l, 16, 0, 0);
}

// ---------------------------------------------------------------------------
// K0: weights fp32 -> bf16 transposed; zero vB k-pad (tile 312); zero counts
// ---------------------------------------------------------------------------
__global__ void k_conv(const float* __restrict__ W1, const float* __restrict__ W2,
                       const float* __restrict__ Wl1, const float* __restrict__ Wl2,
                       unsigned short* __restrict__ W1T, unsigned short* __restrict__ W2T,
                       unsigned short* __restrict__ Wl1T, unsigned short* __restrict__ Wl2T,
                       unsigned short* __restrict__ vB, int* __restrict__ counts) {
  int i = blockIdx.x * 256 + threadIdx.x;
  if (i < 131072) {
    { int k = i >> 9, o = i & 511; W1T[o * 256 + k] = f2bf(W1[i]); }
    { int k = i >> 8, o = i & 255; W2T[o * 512 + k] = f2bf(W2[i]); }
    if (i < 65536) {
      int k = i >> 8, o = i & 255;
      Wl1T[o * 256 + k] = f2bf(Wl1[i]);
      Wl2T[o * 256 + k] = f2bf(Wl2[i]);
    }
    if (i < 4096) {  // zero vB tile 312, kk in [16,32), swizzled address
      int c = i >> 4, kk = 16 + (i & 15);
      int g = kk >> 3;
      int byte = c * 64 + ((g ^ ((c >> 1) & 3)) << 4) + (kk & 7) * 2;
      *(unsigned short*)((char*)vB + (size_t)312 * 16384 + byte) = 0;
    }
    if (i < NN) counts[i] = 0;
  }
}

// ---------------------------------------------------------------------------
// K1: v = relu(vc + relu(vc@W1+b1)@W2 + b2) -> v_rm [N][256] and
//     vB [313 tiles][256 cols][32 k] bf16, byte-swizzled (B of A@v)
// ---------------------------------------------------------------------------
__launch_bounds__(256, 2)
__global__ void k_mlp(const float* __restrict__ vc,
                      const unsigned short* __restrict__ W1T, const float* __restrict__ b1,
                      const unsigned short* __restrict__ W2T, const float* __restrict__ b2,
                      unsigned short* __restrict__ v_rm, unsigned short* __restrict__ vB) {
  __shared__ __align__(16) char sm[65536];
  const int t = threadIdx.x;
  const int lane = t & 63, wid = t >> 6;
  const int wr = wid & 1, wc = wid >> 1;
  const int r0 = blockIdx.x * 32;

  {  // stage vc tile -> bf16
    const int row = t >> 3, grow = r0 + row;
#pragma unroll
    for (int q = 0; q < 4; ++q) {
      const int slot = (t & 7) * 4 + q;
      float buf[8] = {0.f, 0.f, 0.f, 0.f, 0.f, 0.f, 0.f, 0.f};
      if (grow < NN) {
        const float4 x0 = *(const float4*)(vc + (size_t)grow * DIMV + slot * 8);
        const float4 x1 = *(const float4*)(vc + (size_t)grow * DIMV + slot * 8 + 4);
        buf[0] = x0.x; buf[1] = x0.y; buf[2] = x0.z; buf[3] = x0.w;
        buf[4] = x1.x; buf[5] = x1.y; buf[6] = x1.z; buf[7] = x1.w;
      }
      *(bf16x8*)(sm + row * 512 + ((slot ^ (row & 7)) * 16)) = pack8(buf);
    }
  }

  f32x4 acc1[16];
#pragma unroll
  for (int i = 0; i < 16; ++i) acc1[i] = (f32x4){0.f, 0.f, 0.f, 0.f};

  for (int step = 0; step < 8; ++step) {
    __syncthreads();
#pragma unroll
    for (int rr = 0; rr < 2; ++rr) {
      const int c = t + rr * 256;
      const unsigned short* srcp = W1T + c * 256 + step * 32;
#pragma unroll
      for (int q = 0; q < 4; ++q) {
        bf16x8 w = *(const bf16x8*)(srcp + q * 8);
        *(bf16x8*)(sm + 16384 + c * 64 + ((q ^ ((c >> 1) & 3)) * 16)) = w;
      }
    }
    __syncthreads();
    const int arow = 16 * wr + (lane & 15);
    const int aslot = step * 4 + (lane >> 4);
    const bf16x8 af = *(const bf16x8*)(sm + arow * 512 + ((aslot ^ (arow & 7)) * 16));
#pragma unroll
    for (int ct = 0; ct < 16; ++ct) {
      const int c = 256 * wc + 16 * ct + (lane & 15);
      const bf16x8 bfr =
          *(const bf16x8*)(sm + 16384 + c * 64 + ((((lane >> 4)) ^ ((c >> 1) & 3)) * 16));
      acc1[ct] = __builtin_amdgcn_mfma_f32_16x16x32_bf16(af, bfr, acc1[ct], 0, 0, 0);
    }
  }
  __syncthreads();
#pragma unroll
  for (int ct = 0; ct < 16; ++ct) {
    const int c = 256 * wc + 16 * ct + (lane & 15);
    const float bb = b1[c];
#pragma unroll
    for (int r = 0; r < 4; ++r) {
      const int row = 16 * wr + (lane >> 4) * 4 + r;
      float v = fmaxf(acc1[ct][r] + bb, 0.f);
      const int slot = c >> 3;
      *(unsigned short*)(sm + 16384 + row * 1024 + ((slot ^ (row & 7)) * 16) + (c & 7) * 2) =
          f2bf(v);
    }
  }

  f32x4 acc2[8];
#pragma unroll
  for (int i = 0; i < 8; ++i) acc2[i] = (f32x4){0.f, 0.f, 0.f, 0.f};

  for (int step = 0; step < 16; ++step) {
    __syncthreads();
    {
      const int c = t;
      const unsigned short* srcp = W2T + c * 512 + step * 32;
#pragma unroll
      for (int q = 0; q < 4; ++q) {
        bf16x8 w = *(const bf16x8*)(srcp + q * 8);
        *(bf16x8*)(sm + 49152 + c * 64 + ((q ^ ((c >> 1) & 3)) * 16)) = w;
      }
    }
    __syncthreads();
    const int arow = 16 * wr + (lane & 15);
    const int aslot = step * 4 + (lane >> 4);
    const bf16x8 af = *(const bf16x8*)(sm + 16384 + arow * 1024 + ((aslot ^ (arow & 7)) * 16));
#pragma unroll
    for (int ct = 0; ct < 8; ++ct) {
      const int c = 128 * wc + 16 * ct + (lane & 15);
      const bf16x8 bfr =
          *(const bf16x8*)(sm + 49152 + c * 64 + ((((lane >> 4)) ^ ((c >> 1) & 3)) * 16));
      acc2[ct] = __builtin_amdgcn_mfma_f32_16x16x32_bf16(af, bfr, acc2[ct], 0, 0, 0);
    }
  }

  const int growbase = r0 + 16 * wr + (lane >> 4) * 4;
  if (growbase < NN) {
#pragma unroll
    for (int ct = 0; ct < 8; ++ct) {
      const int c = 128 * wc + 16 * ct + (lane & 15);
      const float bb = b2[c];
      u16x4 pk;
#pragma unroll
      for (int r = 0; r < 4; ++r) {
        const int grow = growbase + r;
        float v = acc2[ct][r] + bb + vc[(size_t)grow * DIMV + c];
        v = fmaxf(v, 0.f);
        const unsigned short hv = f2bf(v);
        v_rm[(size_t)grow * DIMV + c] = hv;
        pk[r] = hv;
      }
      const int tile = growbase >> 5, kk0 = growbase & 31;
      const int g = kk0 >> 3;
      const int byte = c * 64 + ((g ^ ((c >> 1) & 3)) << 4) + (kk0 & 7) * 2;
      *(u16x4*)((char*)vB + (size_t)tile * 16384 + byte) = pk;
    }
  }
}

// ---------------------------------------------------------------------------
// K2: Av = A @ v. BM=128, BN=256, BK=32, 512 thr (8 waves: 2 wr x 4 wc).
// A: reg-stage fp32 -> cvt -> bf16 LDS, plane layout [4][128][16B] (+64B pad),
//    double-buffered. B: glds from pre-swizzled vB (dbuf). 1 barrier/step.
// acc = 16 frags/wave (64 AGPR) -> 2 blocks/CU. grid 474, bijective XCD remap.
// ---------------------------------------------------------------------------
__launch_bounds__(512, 4)
__global__ void k_av(const float* __restrict__ A, const unsigned short* __restrict__ vB,
                     unsigned short* __restrict__ avpb) {
  __shared__ __align__(16) char sm[LDSZ];
  const int t = threadIdx.x, lane = t & 63, wid = t >> 6;
  const int wr = wid >> 2, wc = wid & 3;

  // bijective XCD-chunked remap of 474 blocks (m204 form)
  const int orig = blockIdx.x;
  const int xcd = orig & 7, idx = orig >> 3;
  const int g = (xcd < 2) ? xcd * 60 + idx : 120 + (xcd - 2) * 59 + idx;
  const int s = g / 79;          // k-chunk 0..5
  const int xb = g - s * 79;     // row-block 0..78
  const int r0 = xb * 128;
  const int kbase = s * KCH;
  const int tile0 = s * 52;
  const int nst = (s == SPLIT - 1) ? 53 : 52;
  unsigned short* outp = avpb + (size_t)s * NN * DIMV;

  // --- A staging roles: 2 pieces; piece p rows = p*64 + (t>>3); sQ = t&7
  const int srow = t >> 3, sQ = t & 7;
  const float* ap0 = A + (size_t)min(r0 + srow, NN - 1) * NN;
  const float* ap1 = A + (size_t)min(r0 + 64 + srow, NN - 1) * NN;
  // LDS write: plane p = sQ>>1, half h = sQ&1: addr = p*APL + row*16 + h*8
  const int wbase = (sQ >> 1) * APL + (sQ & 1) * 8;
  const int w0 = wbase + srow * 16;
  const int w1 = wbase + (64 + srow) * 16;

  f32x4 aR0, aR1;

#define AISSUE(ST)                                            \
  do {                                                        \
    int kq = kbase + (ST)*32 + sQ * 4;                        \
    kq = min(kq, 9996); /* overshoot -> B pad zeros */        \
    aR0 = *(const f32x4*)(ap0 + kq);                          \
    aR1 = *(const f32x4*)(ap1 + kq);                          \
  } while (0)

#define AWRITE(BUF)                                           \
  do {                                                        \
    char* wb = sm + (BUF)*ABUF;                               \
    *(u32x2*)(wb + w0) = cvt4v(aR0);                          \
    *(u32x2*)(wb + w1) = cvt4v(aR1);                          \
  } while (0)

#define BSTAGE(BUF, TILE)                                                     \
  do {                                                                        \
    char* lb = sm + BOFF + (BUF)*16384 + wid * 1024;                          \
    const char* gp = (const char*)vB + (size_t)(TILE)*16384 + wid * 1024 +    \
                     lane * 16;                                               \
    glds16(gp, lb);                                                           \
    glds16(gp + 8192, lb + 8192);                                             \
  } while (0)

  f32x4 acc[4][4];
#pragma unroll
  for (int i = 0; i < 4; ++i)
#pragma unroll
    for (int j = 0; j < 4; ++j) acc[i][j] = (f32x4){0.f, 0.f, 0.f, 0.f};

  // A-frag read offsets: plane p = lane>>4; row = wr*64 + rt*16 + (lane&15)
  const int rbase = (lane >> 4) * APL + (wr * 64 + (lane & 15)) * 16;
  // B-frag read offsets per ct
  int boff[4];
#pragma unroll
  for (int ct = 0; ct < 4; ++ct) {
    const int col = wc * 64 + ct * 16 + (lane & 15);
    boff[ct] = col * 64 + (((lane >> 4) ^ ((col >> 1) & 3)) << 4);
  }

#define COMPUTE(CUR)                                                                 \
  do {                                                                              \
    const char* ab = sm + (CUR)*ABUF;                                               \
    const char* bb = sm + BOFF + (CUR)*16384;                                       \
    const bf16x8 af0 = *(const bf16x8*)(ab + rbase);                                \
    const bf16x8 af1 = *(const bf16x8*)(ab + rbase + 256);                          \
    const bf16x8 af2 = *(const bf16x8*)(ab + rbase + 512);                          \
    const bf16x8 af3 = *(const bf16x8*)(ab + rbase + 768);                          \
    _Pragma("unroll") for (int ct = 0; ct < 4; ++ct) {                              \
      const bf16x8 bfr = *(const bf16x8*)(bb + boff[ct]);                           \
      acc[0][ct] = __builtin_amdgcn_mfma_f32_16x16x32_bf16(af0, bfr, acc[0][ct], 0, 0, 0); \
      acc[1][ct] = __builtin_amdgcn_mfma_f32_16x16x32_bf16(af1, bfr, acc[1][ct], 0, 0, 0); \
      acc[2][ct] = __builtin_amdgcn_mfma_f32_16x16x32_bf16(af2, bfr, acc[2][ct], 0, 0, 0); \
      acc[3][ct] = __builtin_amdgcn_mfma_f32_16x16x32_bf16(af3, bfr, acc[3][ct], 0, 0, 0); \
    }                                                                               \
  } while (0)

  // prologue
  AISSUE(0);
  AWRITE(0);
  BSTAGE(0, tile0);
  __syncthreads();

  int cur = 0;
  for (int st = 0; st < nst; ++st) {
    const bool more = (st + 1 < nst);
    if (more) {
      AISSUE(st + 1);                  // A HBM loads first (long pole)
      BSTAGE(cur ^ 1, tile0 + st + 1); // then B glds (L2)
    }
    COMPUTE(cur);
    if (more) AWRITE(cur ^ 1);         // cvt+ds_write after MFMA cluster
    __syncthreads();
    cur ^= 1;
  }
#undef AISSUE
#undef AWRITE
#undef BSTAGE
#undef COMPUTE

  // epilogue: bf16 partials
#pragma unroll
  for (int rt = 0; rt < 4; ++rt) {
    const int gb = r0 + wr * 64 + rt * 16 + (lane >> 4) * 4;
    if (gb < NN) {
#pragma unroll
      for (int ct = 0; ct < 4; ++ct) {
        const int col = wc * 64 + ct * 16 + (lane & 15);
#pragma unroll
        for (int r = 0; r < 4; ++r)
          outp[(size_t)(gb + r) * DIMV + col] = f2bf(acc[rt][ct][r]);
      }
    }
  }
}

// ---------------------------------------------------------------------------
// K3: v2 = relu(v@Wl1+bl1) + relu((sum_p avpb[p])@Wl2+bl2)
//     writes d_out (fp32) and v2b (bf16, for gather)
// ---------------------------------------------------------------------------
__launch_bounds__(256, 2)
__global__ void k_out(const unsigned short* __restrict__ v_rm,
                      const unsigned short* __restrict__ avpb,
                      const unsigned short* __restrict__ Wl1T, const float* __restrict__ bl1,
                      const unsigned short* __restrict__ Wl2T, const float* __restrict__ bl2,
                      unsigned short* __restrict__ v2b, float* __restrict__ outb) {
  __shared__ __align__(16) char sm[65536];
  const int t = threadIdx.x, lane = t & 63, wid = t >> 6;
  const int wr = wid & 1, wc = wid >> 1;
  const int r0 = blockIdx.x * 32;

  {
    const int row = t >> 3, grow = r0 + row;
#pragma unroll
    for (int q = 0; q < 4; ++q) {
      const int slot = (t & 7) * 4 + q;
      bf16x8 w = (grow < NN) ? *(const bf16x8*)(v_rm + (size_t)grow * DIMV + slot * 8) : bzero8();
      *(bf16x8*)(sm + row * 512 + ((slot ^ (row & 7)) * 16)) = w;
    }
#pragma unroll
    for (int q = 0; q < 4; ++q) {
      const int slot = (t & 7) * 4 + q;
      float buf[8] = {0.f, 0.f, 0.f, 0.f, 0.f, 0.f, 0.f, 0.f};
      if (grow < NN) {
#pragma unroll
        for (int p = 0; p < SPLIT; ++p) {
          const bf16x8 a =
              *(const bf16x8*)(avpb + (size_t)p * NN * DIMV + (size_t)grow * DIMV + slot * 8);
#pragma unroll
          for (int z = 0; z < 8; ++z) buf[z] += bf2f((unsigned short)a[z]);
        }
      }
      *(bf16x8*)(sm + 16384 + row * 512 + ((slot ^ (row & 7)) * 16)) = pack8(buf);
    }
  }

  f32x4 acc1[8], acc2[8];
#pragma unroll
  for (int i = 0; i < 8; ++i) {
    acc1[i] = (f32x4){0.f, 0.f, 0.f, 0.f};
    acc2[i] = (f32x4){0.f, 0.f, 0.f, 0.f};
  }

  for (int step = 0; step < 8; ++step) {
    __syncthreads();
    {
      const int c = t;
      const unsigned short* s1 = Wl1T + c * 256 + step * 32;
      const unsigned short* s2 = Wl2T + c * 256 + step * 32;
#pragma unroll
      for (int q = 0; q < 4; ++q) {
        const int ps = (q ^ ((c >> 1) & 3)) * 16;
        *(bf16x8*)(sm + 32768 + c * 64 + ps) = *(const bf16x8*)(s1 + q * 8);
        *(bf16x8*)(sm + 49152 + c * 64 + ps) = *(const bf16x8*)(s2 + q * 8);
      }
    }
    __syncthreads();
    const int arow = 16 * wr + (lane & 15);
    const int aslot = step * 4 + (lane >> 4);
    const bf16x8 a1 = *(const bf16x8*)(sm + arow * 512 + ((aslot ^ (arow & 7)) * 16));
    const bf16x8 a2 = *(const bf16x8*)(sm + 16384 + arow * 512 + ((aslot ^ (arow & 7)) * 16));
#pragma unroll
    for (int ct = 0; ct < 8; ++ct) {
      const int c = 128 * wc + 16 * ct + (lane & 15);
      const int bs = (((lane >> 4)) ^ ((c >> 1) & 3)) * 16;
      acc1[ct] = __builtin_amdgcn_mfma_f32_16x16x32_bf16(
          a1, *(const bf16x8*)(sm + 32768 + c * 64 + bs), acc1[ct], 0, 0, 0);
      acc2[ct] = __builtin_amdgcn_mfma_f32_16x16x32_bf16(
          a2, *(const bf16x8*)(sm + 49152 + c * 64 + bs), acc2[ct], 0, 0, 0);
    }
  }

  const int growbase = r0 + 16 * wr + (lane >> 4) * 4;
  if (growbase < NN) {
#pragma unroll
    for (int ct = 0; ct < 8; ++ct) {
      const int c = 128 * wc + 16 * ct + (lane & 15);
      const float u1 = bl1[c], u2 = bl2[c];
#pragma unroll
      for (int r = 0; r < 4; ++r) {
        const float x = fmaxf(acc1[ct][r] + u1, 0.f) + fmaxf(acc2[ct][r] + u2, 0.f);
        v2b[(size_t)(growbase + r) * DIMV + c] = f2bf(x);
        outb[(size_t)(growbase + r) * DIMV + c] = x;
      }
    }
  }
}

// ---------------------------------------------------------------------------
__global__ void k_hist(const int* __restrict__ dst, int* __restrict__ counts) {
  const int e = blockIdx.x * 256 + threadIdx.x;
  if (e < NEDGE) atomicAdd(&counts[dst[e]], 1);
}

// single-block shuffle-based two-level exclusive scan
__global__ void k_scan(const int* __restrict__ counts, int* __restrict__ offsets,
                       int* __restrict__ cursor) {
  __shared__ int wred[16];
  __shared__ int chtot;
  const int t = threadIdx.x;
  const int lane = t & 63, wid = t >> 6;
  int carry = 0;
  for (int base = 0; base < NN; base += 1024) {
    const int i = base + t;
    const int x = (i < NN) ? counts[i] : 0;
    int v = x;
#pragma unroll
    for (int d = 1; d < 64; d <<= 1) {
      int y = __shfl_up(v, d);
      if (lane >= d) v += y;
    }
    if (lane == 63) wred[wid] = v;
    __syncthreads();
    if (t < 16) {
      int sv = wred[t];
#pragma unroll
      for (int d = 1; d < 16; d <<= 1) {
        int y = __shfl_up(sv, d);
        if (t >= d) sv += y;
      }
      wred[t] = sv;
      if (t == 15) chtot = sv;
    }
    __syncthreads();
    const int woff = wid ? wred[wid - 1] : 0;
    const int excl = carry + woff + v - x;
    if (i < NN) { offsets[i] = excl; cursor[i] = excl; }
    carry += chtot;
    __syncthreads();
  }
  if (t == 0) offsets[NN] = carry;
}

__global__ void k_fill(const int* __restrict__ src, const int* __restrict__ dst,
                       int* __restrict__ cursor, int* __restrict__ srcbuf) {
  const int e = blockIdx.x * 256 + threadIdx.x;
  if (e < NEDGE) {
    const int pos = atomicAdd(&cursor[dst[e]], 1);
    srcbuf[pos] = src[e];
  }
}

// ---------------------------------------------------------------------------
// K4d: gather-sum from bf16 v2b; one wave per dst node; lane owns 4 cols.
// ---------------------------------------------------------------------------
__launch_bounds__(256)
__global__ void k_gather(const unsigned short* __restrict__ v2b,
                         const int* __restrict__ offsets,
                         const int* __restrict__ srcbuf, float* __restrict__ outb) {
  const int n = (blockIdx.x * 256 + threadIdx.x) >> 6;
  if (n >= NN) return;
  const int lane = threadIdx.x & 63;
  const int beg = offsets[n], end = offsets[n + 1];
  float4 a0 = {0.f, 0.f, 0.f, 0.f}, a1 = a0, a2 = a0, a3 = a0;
  int j = beg;
  for (; j + 4 <= end; j += 4) {
    const int s0 = srcbuf[j], s1 = srcbuf[j + 1], s2 = srcbuf[j + 2], s3 = srcbuf[j + 3];
    const u16x4 x0 = *(const u16x4*)(v2b + (size_t)s0 * DIMV + lane * 4);
    const u16x4 x1 = *(const u16x4*)(v2b + (size_t)s1 * DIMV + lane * 4);
    const u16x4 x2 = *(const u16x4*)(v2b + (size_t)s2 * DIMV + lane * 4);
    const u16x4 x3 = *(const u16x4*)(v2b + (size_t)s3 * DIMV + lane * 4);
    a0.x += bf2f(x0[0]); a0.y += bf2f(x0[1]); a0.z += bf2f(x0[2]); a0.w += bf2f(x0[3]);
    a1.x += bf2f(x1[0]); a1.y += bf2f(x1[1]); a1.z += bf2f(x1[2]); a1.w += bf2f(x1[3]);
    a2.x += bf2f(x2[0]); a2.y += bf2f(x2[1]); a2.z += bf2f(x2[2]); a2.w += bf2f(x2[3]);
    a3.x += bf2f(x3[0]); a3.y += bf2f(x3[1]); a3.z += bf2f(x3[2]); a3.w += bf2f(x3[3]);
  }
  for (; j < end; ++j) {
    const int s0 = srcbuf[j];
    const u16x4 x0 = *(const u16x4*)(v2b + (size_t)s0 * DIMV + lane * 4);
    a0.x += bf2f(x0[0]); a0.y += bf2f(x0[1]); a0.z += bf2f(x0[2]); a0.w += bf2f(x0[3]);
  }
  a0.x += a1.x + a2.x + a3.x; a0.y += a1.y + a2.y + a3.y;
  a0.z += a1.z + a2.z + a3.z; a0.w += a1.w + a2.w + a3.w;
  float* o = outb + (size_t)n * DIMV + lane * 4;
  float4 cur = *(const float4*)o;
  cur.x += a0.x; cur.y += a0.y; cur.z += a0.z; cur.w += a0.w;
  *(float4*)o = cur;
}

// ---------------------------------------------------------------------------
extern "C" void kernel_launch(void* const* d_in, const int* in_sizes, int n_in,
                              void* d_out, int out_size, void* d_ws, size_t ws_size,
                              hipStream_t stream) {
  const float* vc  = (const float*)d_in[0];
  const float* A   = (const float*)d_in[1];
  const int*   src = (const int*)d_in[2];
  const int*   dst = (const int*)d_in[3];
  const float* W1  = (const float*)d_in[4];
  const float* b1  = (const float*)d_in[5];
  const float* W2  = (const float*)d_in[6];
  const float* b2  = (const float*)d_in[7];
  const float* Wl1 = (const float*)d_in[8];
  const float* bl1 = (const float*)d_in[9];
  const float* Wl2 = (const float*)d_in[10];
  const float* bl2 = (const float*)d_in[11];
  float* outb = (float*)d_out;
  char* ws = (char*)d_ws;

  // carve (bytes), no aliasing:
  unsigned short* W1T  = (unsigned short*)(ws + 0);
  unsigned short* W2T  = (unsigned short*)(ws + 262144);
  unsigned short* Wl1T = (unsigned short*)(ws + 524288);
  unsigned short* Wl2T = (unsigned short*)(ws + 655360);
  unsigned short* vB   = (unsigned short*)(ws + 786432);     // 313 x 16KB tiles
  unsigned short* v_rm = (unsigned short*)(ws + 5914624);    // [10000][256] bf16
  int* counts  = (int*)(ws + 11034624);
  int* offsets = (int*)(ws + 11075584);
  int* cursor  = (int*)(ws + 11116544);
  int* srcbuf  = (int*)(ws + 11157504);                       // 1.28 MB
  unsigned short* avpb = (unsigned short*)(ws + 12437760);    // SPLIT x [N][256] bf16 (30.7MB)
  unsigned short* v2b  = (unsigned short*)(ws + 43157760);    // [N][256] bf16
  // total ~48.3 MB

  hipLaunchKernelGGL(k_conv, dim3(512), dim3(256), 0, stream,
                     W1, W2, Wl1, Wl2, W1T, W2T, Wl1T, Wl2T, vB, counts);
  hipLaunchKernelGGL(k_hist, dim3((NEDGE + 255) / 256), dim3(256), 0, stream, dst, counts);
  hipLaunchKernelGGL(k_scan, dim3(1), dim3(1024), 0, stream, counts, offsets, cursor);
  hipLaunchKernelGGL(k_fill, dim3((NEDGE + 255) / 256), dim3(256), 0, stream,
                     src, dst, cursor, srcbuf);
  hipLaunchKernelGGL(k_mlp, dim3(313), dim3(256), 0, stream,
                     vc, W1T, b1, W2T, b2, v_rm, vB);
  hipLaunchKernelGGL(k_av, dim3(474), dim3(512), 0, stream, A, vB, avpb);
  hipLaunchKernelGGL(k_out, dim3(313), dim3(256), 0, stream,
                     v_rm, avpb, Wl1T, bl1, Wl2T, bl2, v2b, outb);
  hipLaunchKernelGGL(k_gather, dim3((NN * 64 + 255) / 256), dim3(256), 0, stream,
                     v2b, offsets, srcbuf, outb);
}

// Round 8
// 236.551 us; speedup vs baseline: 2.5861x; 1.0922x over previous
//
#include <hip/hip_runtime.h>
#include <stdint.h>

#define NN 10000
#define DIMV 256
#define HID 512
#define NEDGE 320000
#define SPLIT 6
#define KCH 1664      // k per chunk (52 tiles); chunk 5: 53 tiles incl. zero-pad tile 312
#define NKT 313
#define APL 2112      // A LDS plane stride bytes (128*16 + 64 pad)
#define ABUF 8448     // 4*APL
#define BOFF 16896    // 2*ABUF
#define LDSZ 49664    // BOFF + 2*16384

typedef __attribute__((ext_vector_type(8))) short bf16x8;
typedef __attribute__((ext_vector_type(4))) float f32x4;
typedef __attribute__((ext_vector_type(4))) unsigned short u16x4;
typedef __attribute__((ext_vector_type(2))) unsigned int u32x2;

__device__ __forceinline__ unsigned short f2bf(float f) {
  union { float f; unsigned int u; } c; c.f = f;
  return (unsigned short)((c.u + 0x7FFFu + ((c.u >> 16) & 1u)) >> 16);
}
__device__ __forceinline__ float bf2f(unsigned short h) {
  union { unsigned int u; float f; } c; c.u = ((unsigned int)h) << 16;
  return c.f;
}

__device__ __forceinline__ bf16x8 bzero8() {
  bf16x8 r;
#pragma unroll
  for (int i = 0; i < 8; ++i) r[i] = 0;
  return r;
}

__device__ __forceinline__ bf16x8 pack8(const float* x) {
  bf16x8 r;
#pragma unroll
  for (int i = 0; i < 8; ++i) r[i] = (short)f2bf(x[i]);
  return r;
}

// f32x4 -> 4 packed bf16 (8B) via v_cvt_pk_bf16_f32 (RNE, matches f2bf)
__device__ __forceinline__ u32x2 cvt4v(const f32x4 a) {
  u32x2 r;
  asm("v_cvt_pk_bf16_f32 %0, %1, %2" : "=v"(r[0]) : "v"(a[0]), "v"(a[1]));
  asm("v_cvt_pk_bf16_f32 %0, %1, %2" : "=v"(r[1]) : "v"(a[2]), "v"(a[3]));
  return r;
}

// async global->LDS, 16B/lane; LDS dest = wave-uniform base + lane*16
typedef __attribute__((address_space(1))) unsigned int gu32;
typedef __attribute__((address_space(3))) unsigned int lu32;
__device__ __forceinline__ void glds16(const void* g, void* l) {
  __builtin_amdgcn_global_load_lds((const gu32*)g, (lu32*)l, 16, 0, 0);
}

// ---------------------------------------------------------------------------
// K0: weights fp32 -> bf16 transposed; zero vB k-pad (tile 312); zero counts
// ---------------------------------------------------------------------------
__global__ void k_conv(const float* __restrict__ W1, const float* __restrict__ W2,
                       const float* __restrict__ Wl1, const float* __restrict__ Wl2,
                       unsigned short* __restrict__ W1T, unsigned short* __restrict__ W2T,
                       unsigned short* __restrict__ Wl1T, unsigned short* __restrict__ Wl2T,
                       unsigned short* __restrict__ vB, int* __restrict__ counts) {
  int i = blockIdx.x * 256 + threadIdx.x;
  if (i < 131072) {
    { int k = i >> 9, o = i & 511; W1T[o * 256 + k] = f2bf(W1[i]); }
    { int k = i >> 8, o = i & 255; W2T[o * 512 + k] = f2bf(W2[i]); }
    if (i < 65536) {
      int k = i >> 8, o = i & 255;
      Wl1T[o * 256 + k] = f2bf(Wl1[i]);
      Wl2T[o * 256 + k] = f2bf(Wl2[i]);
    }
    if (i < 4096) {  // zero vB tile 312, kk in [16,32), swizzled address
      int c = i >> 4, kk = 16 + (i & 15);
      int g = kk >> 3;
      int byte = c * 64 + ((g ^ ((c >> 1) & 3)) << 4) + (kk & 7) * 2;
      *(unsigned short*)((char*)vB + (size_t)312 * 16384 + byte) = 0;
    }
    if (i < NN) counts[i] = 0;
  }
}

// ---------------------------------------------------------------------------
// K1: blocks 0..312: v = relu(vc + relu(vc@W1+b1)@W2 + b2) -> v_rm, vB
//     blocks 313..352: dst histogram (needs counts=0 from k_conv)
// ---------------------------------------------------------------------------
__launch_bounds__(256, 2)
__global__ void k_mlp(const float* __restrict__ vc,
                      const unsigned short* __restrict__ W1T, const float* __restrict__ b1,
                      const unsigned short* __restrict__ W2T, const float* __restrict__ b2,
                      unsigned short* __restrict__ v_rm, unsigned short* __restrict__ vB,
                      const int* __restrict__ dst, int* __restrict__ counts) {
  if (blockIdx.x >= 313) {  // fused histogram
    const int e0 = (blockIdx.x - 313) * 256 + threadIdx.x;
    for (int e = e0; e < NEDGE; e += 40 * 256) atomicAdd(&counts[dst[e]], 1);
    return;
  }
  __shared__ __align__(16) char sm[65536];
  const int t = threadIdx.x;
  const int lane = t & 63, wid = t >> 6;
  const int wr = wid & 1, wc = wid >> 1;
  const int r0 = blockIdx.x * 32;

  {  // stage vc tile -> bf16
    const int row = t >> 3, grow = r0 + row;
#pragma unroll
    for (int q = 0; q < 4; ++q) {
      const int slot = (t & 7) * 4 + q;
      float buf[8] = {0.f, 0.f, 0.f, 0.f, 0.f, 0.f, 0.f, 0.f};
      if (grow < NN) {
        const float4 x0 = *(const float4*)(vc + (size_t)grow * DIMV + slot * 8);
        const float4 x1 = *(const float4*)(vc + (size_t)grow * DIMV + slot * 8 + 4);
        buf[0] = x0.x; buf[1] = x0.y; buf[2] = x0.z; buf[3] = x0.w;
        buf[4] = x1.x; buf[5] = x1.y; buf[6] = x1.z; buf[7] = x1.w;
      }
      *(bf16x8*)(sm + row * 512 + ((slot ^ (row & 7)) * 16)) = pack8(buf);
    }
  }

  f32x4 acc1[16];
#pragma unroll
  for (int i = 0; i < 16; ++i) acc1[i] = (f32x4){0.f, 0.f, 0.f, 0.f};

  for (int step = 0; step < 8; ++step) {
    __syncthreads();
#pragma unroll
    for (int rr = 0; rr < 2; ++rr) {
      const int c = t + rr * 256;
      const unsigned short* srcp = W1T + c * 256 + step * 32;
#pragma unroll
      for (int q = 0; q < 4; ++q) {
        bf16x8 w = *(const bf16x8*)(srcp + q * 8);
        *(bf16x8*)(sm + 16384 + c * 64 + ((q ^ ((c >> 1) & 3)) * 16)) = w;
      }
    }
    __syncthreads();
    const int arow = 16 * wr + (lane & 15);
    const int aslot = step * 4 + (lane >> 4);
    const bf16x8 af = *(const bf16x8*)(sm + arow * 512 + ((aslot ^ (arow & 7)) * 16));
#pragma unroll
    for (int ct = 0; ct < 16; ++ct) {
      const int c = 256 * wc + 16 * ct + (lane & 15);
      const bf16x8 bfr =
          *(const bf16x8*)(sm + 16384 + c * 64 + ((((lane >> 4)) ^ ((c >> 1) & 3)) * 16));
      acc1[ct] = __builtin_amdgcn_mfma_f32_16x16x32_bf16(af, bfr, acc1[ct], 0, 0, 0);
    }
  }
  __syncthreads();
#pragma unroll
  for (int ct = 0; ct < 16; ++ct) {
    const int c = 256 * wc + 16 * ct + (lane & 15);
    const float bb = b1[c];
#pragma unroll
    for (int r = 0; r < 4; ++r) {
      const int row = 16 * wr + (lane >> 4) * 4 + r;
      float v = fmaxf(acc1[ct][r] + bb, 0.f);
      const int slot = c >> 3;
      *(unsigned short*)(sm + 16384 + row * 1024 + ((slot ^ (row & 7)) * 16) + (c & 7) * 2) =
          f2bf(v);
    }
  }

  f32x4 acc2[8];
#pragma unroll
  for (int i = 0; i < 8; ++i) acc2[i] = (f32x4){0.f, 0.f, 0.f, 0.f};

  for (int step = 0; step < 16; ++step) {
    __syncthreads();
    {
      const int c = t;
      const unsigned short* srcp = W2T + c * 512 + step * 32;
#pragma unroll
      for (int q = 0; q < 4; ++q) {
        bf16x8 w = *(const bf16x8*)(srcp + q * 8);
        *(bf16x8*)(sm + 49152 + c * 64 + ((q ^ ((c >> 1) & 3)) * 16)) = w;
      }
    }
    __syncthreads();
    const int arow = 16 * wr + (lane & 15);
    const int aslot = step * 4 + (lane >> 4);
    const bf16x8 af = *(const bf16x8*)(sm + 16384 + arow * 1024 + ((aslot ^ (arow & 7)) * 16));
#pragma unroll
    for (int ct = 0; ct < 8; ++ct) {
      const int c = 128 * wc + 16 * ct + (lane & 15);
      const bf16x8 bfr =
          *(const bf16x8*)(sm + 49152 + c * 64 + ((((lane >> 4)) ^ ((c >> 1) & 3)) * 16));
      acc2[ct] = __builtin_amdgcn_mfma_f32_16x16x32_bf16(af, bfr, acc2[ct], 0, 0, 0);
    }
  }

  const int growbase = r0 + 16 * wr + (lane >> 4) * 4;
  if (growbase < NN) {
#pragma unroll
    for (int ct = 0; ct < 8; ++ct) {
      const int c = 128 * wc + 16 * ct + (lane & 15);
      const float bb = b2[c];
      u16x4 pk;
#pragma unroll
      for (int r = 0; r < 4; ++r) {
        const int grow = growbase + r;
        float v = acc2[ct][r] + bb + vc[(size_t)grow * DIMV + c];
        v = fmaxf(v, 0.f);
        const unsigned short hv = f2bf(v);
        v_rm[(size_t)grow * DIMV + c] = hv;
        pk[r] = hv;
      }
      const int tile = growbase >> 5, kk0 = growbase & 31;
      const int g = kk0 >> 3;
      const int byte = c * 64 + ((g ^ ((c >> 1) & 3)) << 4) + (kk0 & 7) * 2;
      *(u16x4*)((char*)vB + (size_t)tile * 16384 + byte) = pk;
    }
  }
}

// ---------------------------------------------------------------------------
// K2: blocks 0..473: Av = A @ v (BM=128, BN=256, BK=32, dbuf, 1 barrier/step)
//     block 474: exclusive scan of counts -> offsets, cursor (hist from k_mlp)
// ---------------------------------------------------------------------------
__launch_bounds__(512, 4)
__global__ void k_av(const float* __restrict__ A, const unsigned short* __restrict__ vB,
                     unsigned short* __restrict__ avpb,
                     const int* __restrict__ counts, int* __restrict__ offsets,
                     int* __restrict__ cursor) {
  __shared__ __align__(16) char sm[LDSZ];
  const int t = threadIdx.x, lane = t & 63, wid = t >> 6;

  if (blockIdx.x >= 474) {  // fused exclusive scan (512 threads, 8 waves)
    int* wred = (int*)sm;
    int carry = 0;
    for (int base = 0; base < NN; base += 512) {
      const int i = base + t;
      const int x = (i < NN) ? counts[i] : 0;
      int v = x;
#pragma unroll
      for (int d = 1; d < 64; d <<= 1) {
        int y = __shfl_up(v, d);
        if (lane >= d) v += y;
      }
      if (lane == 63) wred[wid] = v;
      __syncthreads();
      if (t < 8) {
        int sv = wred[t];
#pragma unroll
        for (int d = 1; d < 8; d <<= 1) {
          int y = __shfl_up(sv, d);
          if (t >= d) sv += y;
        }
        wred[t] = sv;
      }
      __syncthreads();
      const int excl = carry + (wid ? wred[wid - 1] : 0) + v - x;
      if (i < NN) { offsets[i] = excl; cursor[i] = excl; }
      carry += wred[7];
      __syncthreads();
    }
    if (t == 0) offsets[NN] = carry;
    return;
  }

  const int wr = wid >> 2, wc = wid & 3;

  // bijective XCD-chunked remap of 474 blocks (m204 form)
  const int orig = blockIdx.x;
  const int xcd = orig & 7, idx = orig >> 3;
  const int g = (xcd < 2) ? xcd * 60 + idx : 120 + (xcd - 2) * 59 + idx;
  const int s = g / 79;          // k-chunk 0..5
  const int xb = g - s * 79;     // row-block 0..78
  const int r0 = xb * 128;
  const int kbase = s * KCH;
  const int tile0 = s * 52;
  const int nst = (s == SPLIT - 1) ? 53 : 52;
  unsigned short* outp = avpb + (size_t)s * NN * DIMV;

  // --- A staging roles: 2 pieces; piece p rows = p*64 + (t>>3); sQ = t&7
  const int srow = t >> 3, sQ = t & 7;
  const float* ap0 = A + (size_t)min(r0 + srow, NN - 1) * NN;
  const float* ap1 = A + (size_t)min(r0 + 64 + srow, NN - 1) * NN;
  const int wbase = (sQ >> 1) * APL + (sQ & 1) * 8;
  const int w0 = wbase + srow * 16;
  const int w1 = wbase + (64 + srow) * 16;

  f32x4 aR0, aR1;

#define AISSUE(ST)                                            \
  do {                                                        \
    int kq = kbase + (ST)*32 + sQ * 4;                        \
    kq = min(kq, 9996); /* overshoot -> B pad zeros */        \
    aR0 = *(const f32x4*)(ap0 + kq);                          \
    aR1 = *(const f32x4*)(ap1 + kq);                          \
  } while (0)

#define AWRITE(BUF)                                           \
  do {                                                        \
    char* wb = sm + (BUF)*ABUF;                               \
    *(u32x2*)(wb + w0) = cvt4v(aR0);                          \
    *(u32x2*)(wb + w1) = cvt4v(aR1);                          \
  } while (0)

#define BSTAGE(BUF, TILE)                                                     \
  do {                                                                        \
    char* lb = sm + BOFF + (BUF)*16384 + wid * 1024;                          \
    const char* gp = (const char*)vB + (size_t)(TILE)*16384 + wid * 1024 +    \
                     lane * 16;                                               \
    glds16(gp, lb);                                                           \
    glds16(gp + 8192, lb + 8192);                                             \
  } while (0)

  f32x4 acc[4][4];
#pragma unroll
  for (int i = 0; i < 4; ++i)
#pragma unroll
    for (int j = 0; j < 4; ++j) acc[i][j] = (f32x4){0.f, 0.f, 0.f, 0.f};

  const int rbase = (lane >> 4) * APL + (wr * 64 + (lane & 15)) * 16;
  int boff[4];
#pragma unroll
  for (int ct = 0; ct < 4; ++ct) {
    const int col = wc * 64 + ct * 16 + (lane & 15);
    boff[ct] = col * 64 + (((lane >> 4) ^ ((col >> 1) & 3)) << 4);
  }

#define COMPUTE(CUR)                                                                 \
  do {                                                                              \
    const char* ab = sm + (CUR)*ABUF;                                               \
    const char* bb = sm + BOFF + (CUR)*16384;                                       \
    const bf16x8 af0 = *(const bf16x8*)(ab + rbase);                                \
    const bf16x8 af1 = *(const bf16x8*)(ab + rbase + 256);                          \
    const bf16x8 af2 = *(const bf16x8*)(ab + rbase + 512);                          \
    const bf16x8 af3 = *(const bf16x8*)(ab + rbase + 768);                          \
    _Pragma("unroll") for (int ct = 0; ct < 4; ++ct) {                              \
      const bf16x8 bfr = *(const bf16x8*)(bb + boff[ct]);                           \
      acc[0][ct] = __builtin_amdgcn_mfma_f32_16x16x32_bf16(af0, bfr, acc[0][ct], 0, 0, 0); \
      acc[1][ct] = __builtin_amdgcn_mfma_f32_16x16x32_bf16(af1, bfr, acc[1][ct], 0, 0, 0); \
      acc[2][ct] = __builtin_amdgcn_mfma_f32_16x16x32_bf16(af2, bfr, acc[2][ct], 0, 0, 0); \
      acc[3][ct] = __builtin_amdgcn_mfma_f32_16x16x32_bf16(af3, bfr, acc[3][ct], 0, 0, 0); \
    }                                                                               \
  } while (0)

  // prologue
  AISSUE(0);
  AWRITE(0);
  BSTAGE(0, tile0);
  __syncthreads();

  int cur = 0;
  for (int st = 0; st < nst; ++st) {
    const bool more = (st + 1 < nst);
    if (more) {
      AISSUE(st + 1);                  // A HBM loads first (long pole)
      BSTAGE(cur ^ 1, tile0 + st + 1); // then B glds (L2)
    }
    COMPUTE(cur);
    if (more) AWRITE(cur ^ 1);         // cvt+ds_write after MFMA cluster
    __syncthreads();
    cur ^= 1;
  }
#undef AISSUE
#undef AWRITE
#undef BSTAGE
#undef COMPUTE

  // epilogue: bf16 partials
#pragma unroll
  for (int rt = 0; rt < 4; ++rt) {
    const int gb = r0 + wr * 64 + rt * 16 + (lane >> 4) * 4;
    if (gb < NN) {
#pragma unroll
      for (int ct = 0; ct < 4; ++ct) {
        const int col = wc * 64 + ct * 16 + (lane & 15);
#pragma unroll
        for (int r = 0; r < 4; ++r)
          outp[(size_t)(gb + r) * DIMV + col] = f2bf(acc[rt][ct][r]);
      }
    }
  }
}

// ---------------------------------------------------------------------------
// K3: blocks 0..312: v2 = relu(v@Wl1+bl1) + relu((sum_p avpb[p])@Wl2+bl2)
//     blocks 313..352: CSR bucket fill (needs scan from k_av)
// ---------------------------------------------------------------------------
__launch_bounds__(256, 2)
__global__ void k_out(const unsigned short* __restrict__ v_rm,
                      const unsigned short* __restrict__ avpb,
                      const unsigned short* __restrict__ Wl1T, const float* __restrict__ bl1,
                      const unsigned short* __restrict__ Wl2T, const float* __restrict__ bl2,
                      unsigned short* __restrict__ v2b, float* __restrict__ outb,
                      const int* __restrict__ src, const int* __restrict__ dst,
                      int* __restrict__ cursor, int* __restrict__ srcbuf) {
  if (blockIdx.x >= 313) {  // fused bucket fill
    const int e0 = (blockIdx.x - 313) * 256 + threadIdx.x;
    for (int e = e0; e < NEDGE; e += 40 * 256) {
      const int pos = atomicAdd(&cursor[dst[e]], 1);
      srcbuf[pos] = src[e];
    }
    return;
  }
  __shared__ __align__(16) char sm[65536];
  const int t = threadIdx.x, lane = t & 63, wid = t >> 6;
  const int wr = wid & 1, wc = wid >> 1;
  const int r0 = blockIdx.x * 32;

  {
    const int row = t >> 3, grow = r0 + row;
#pragma unroll
    for (int q = 0; q < 4; ++q) {
      const int slot = (t & 7) * 4 + q;
      bf16x8 w = (grow < NN) ? *(const bf16x8*)(v_rm + (size_t)grow * DIMV + slot * 8) : bzero8();
      *(bf16x8*)(sm + row * 512 + ((slot ^ (row & 7)) * 16)) = w;
    }
#pragma unroll
    for (int q = 0; q < 4; ++q) {
      const int slot = (t & 7) * 4 + q;
      float buf[8] = {0.f, 0.f, 0.f, 0.f, 0.f, 0.f, 0.f, 0.f};
      if (grow < NN) {
#pragma unroll
        for (int p = 0; p < SPLIT; ++p) {
          const bf16x8 a =
              *(const bf16x8*)(avpb + (size_t)p * NN * DIMV + (size_t)grow * DIMV + slot * 8);
#pragma unroll
          for (int z = 0; z < 8; ++z) buf[z] += bf2f((unsigned short)a[z]);
        }
      }
      *(bf16x8*)(sm + 16384 + row * 512 + ((slot ^ (row & 7)) * 16)) = pack8(buf);
    }
  }

  f32x4 acc1[8], acc2[8];
#pragma unroll
  for (int i = 0; i < 8; ++i) {
    acc1[i] = (f32x4){0.f, 0.f, 0.f, 0.f};
    acc2[i] = (f32x4){0.f, 0.f, 0.f, 0.f};
  }

  for (int step = 0; step < 8; ++step) {
    __syncthreads();
    {
      const int c = t;
      const unsigned short* s1 = Wl1T + c * 256 + step * 32;
      const unsigned short* s2 = Wl2T + c * 256 + step * 32;
#pragma unroll
      for (int q = 0; q < 4; ++q) {
        const int ps = (q ^ ((c >> 1) & 3)) * 16;
        *(bf16x8*)(sm + 32768 + c * 64 + ps) = *(const bf16x8*)(s1 + q * 8);
        *(bf16x8*)(sm + 49152 + c * 64 + ps) = *(const bf16x8*)(s2 + q * 8);
      }
    }
    __syncthreads();
    const int arow = 16 * wr + (lane & 15);
    const int aslot = step * 4 + (lane >> 4);
    const bf16x8 a1 = *(const bf16x8*)(sm + arow * 512 + ((aslot ^ (arow & 7)) * 16));
    const bf16x8 a2 = *(const bf16x8*)(sm + 16384 + arow * 512 + ((aslot ^ (arow & 7)) * 16));
#pragma unroll
    for (int ct = 0; ct < 8; ++ct) {
      const int c = 128 * wc + 16 * ct + (lane & 15);
      const int bs = (((lane >> 4)) ^ ((c >> 1) & 3)) * 16;
      acc1[ct] = __builtin_amdgcn_mfma_f32_16x16x32_bf16(
          a1, *(const bf16x8*)(sm + 32768 + c * 64 + bs), acc1[ct], 0, 0, 0);
      acc2[ct] = __builtin_amdgcn_mfma_f32_16x16x32_bf16(
          a2, *(const bf16x8*)(sm + 49152 + c * 64 + bs), acc2[ct], 0, 0, 0);
    }
  }

  const int growbase = r0 + 16 * wr + (lane >> 4) * 4;
  if (growbase < NN) {
#pragma unroll
    for (int ct = 0; ct < 8; ++ct) {
      const int c = 128 * wc + 16 * ct + (lane & 15);
      const float u1 = bl1[c], u2 = bl2[c];
#pragma unroll
      for (int r = 0; r < 4; ++r) {
        const float x = fmaxf(acc1[ct][r] + u1, 0.f) + fmaxf(acc2[ct][r] + u2, 0.f);
        v2b[(size_t)(growbase + r) * DIMV + c] = f2bf(x);
        outb[(size_t)(growbase + r) * DIMV + c] = x;
      }
    }
  }
}

// ---------------------------------------------------------------------------
// K4: gather-sum from bf16 v2b; one wave per dst node; 8-deep unrolled.
// ---------------------------------------------------------------------------
__launch_bounds__(256)
__global__ void k_gather(const unsigned short* __restrict__ v2b,
                         const int* __restrict__ offsets,
                         const int* __restrict__ srcbuf, float* __restrict__ outb) {
  const int n = (blockIdx.x * 256 + threadIdx.x) >> 6;
  if (n >= NN) return;
  const int lane = threadIdx.x & 63;
  const int beg = offsets[n], end = offsets[n + 1];
  float4 a0 = {0.f, 0.f, 0.f, 0.f}, a1 = a0, a2 = a0, a3 = a0;
  float4 a4 = a0, a5 = a0, a6 = a0, a7 = a0;
  int j = beg;
  for (; j + 8 <= end; j += 8) {
    const int s0 = srcbuf[j], s1 = srcbuf[j + 1], s2 = srcbuf[j + 2], s3 = srcbuf[j + 3];
    const int s4 = srcbuf[j + 4], s5 = srcbuf[j + 5], s6 = srcbuf[j + 6], s7 = srcbuf[j + 7];
    const u16x4 x0 = *(const u16x4*)(v2b + (size_t)s0 * DIMV + lane * 4);
    const u16x4 x1 = *(const u16x4*)(v2b + (size_t)s1 * DIMV + lane * 4);
    const u16x4 x2 = *(const u16x4*)(v2b + (size_t)s2 * DIMV + lane * 4);
    const u16x4 x3 = *(const u16x4*)(v2b + (size_t)s3 * DIMV + lane * 4);
    const u16x4 x4 = *(const u16x4*)(v2b + (size_t)s4 * DIMV + lane * 4);
    const u16x4 x5 = *(const u16x4*)(v2b + (size_t)s5 * DIMV + lane * 4);
    const u16x4 x6 = *(const u16x4*)(v2b + (size_t)s6 * DIMV + lane * 4);
    const u16x4 x7 = *(const u16x4*)(v2b + (size_t)s7 * DIMV + lane * 4);
    a0.x += bf2f(x0[0]); a0.y += bf2f(x0[1]); a0.z += bf2f(x0[2]); a0.w += bf2f(x0[3]);
    a1.x += bf2f(x1[0]); a1.y += bf2f(x1[1]); a1.z += bf2f(x1[2]); a1.w += bf2f(x1[3]);
    a2.x += bf2f(x2[0]); a2.y += bf2f(x2[1]); a2.z += bf2f(x2[2]); a2.w += bf2f(x2[3]);
    a3.x += bf2f(x3[0]); a3.y += bf2f(x3[1]); a3.z += bf2f(x3[2]); a3.w += bf2f(x3[3]);
    a4.x += bf2f(x4[0]); a4.y += bf2f(x4[1]); a4.z += bf2f(x4[2]); a4.w += bf2f(x4[3]);
    a5.x += bf2f(x5[0]); a5.y += bf2f(x5[1]); a5.z += bf2f(x5[2]); a5.w += bf2f(x5[3]);
    a6.x += bf2f(x6[0]); a6.y += bf2f(x6[1]); a6.z += bf2f(x6[2]); a6.w += bf2f(x6[3]);
    a7.x += bf2f(x7[0]); a7.y += bf2f(x7[1]); a7.z += bf2f(x7[2]); a7.w += bf2f(x7[3]);
  }
  for (; j < end; ++j) {
    const int s0 = srcbuf[j];
    const u16x4 x0 = *(const u16x4*)(v2b + (size_t)s0 * DIMV + lane * 4);
    a0.x += bf2f(x0[0]); a0.y += bf2f(x0[1]); a0.z += bf2f(x0[2]); a0.w += bf2f(x0[3]);
  }
  a0.x += a1.x + a2.x + a3.x + a4.x + a5.x + a6.x + a7.x;
  a0.y += a1.y + a2.y + a3.y + a4.y + a5.y + a6.y + a7.y;
  a0.z += a1.z + a2.z + a3.z + a4.z + a5.z + a6.z + a7.z;
  a0.w += a1.w + a2.w + a3.w + a4.w + a5.w + a6.w + a7.w;
  float* o = outb + (size_t)n * DIMV + lane * 4;
  float4 cur = *(const float4*)o;
  cur.x += a0.x; cur.y += a0.y; cur.z += a0.z; cur.w += a0.w;
  *(float4*)o = cur;
}

// ---------------------------------------------------------------------------
extern "C" void kernel_launch(void* const* d_in, const int* in_sizes, int n_in,
                              void* d_out, int out_size, void* d_ws, size_t ws_size,
                              hipStream_t stream) {
  const float* vc  = (const float*)d_in[0];
  const float* A   = (const float*)d_in[1];
  const int*   src = (const int*)d_in[2];
  const int*   dst = (const int*)d_in[3];
  const float* W1  = (const float*)d_in[4];
  const float* b1  = (const float*)d_in[5];
  const float* W2  = (const float*)d_in[6];
  const float* b2  = (const float*)d_in[7];
  const float* Wl1 = (const float*)d_in[8];
  const float* bl1 = (const float*)d_in[9];
  const float* Wl2 = (const float*)d_in[10];
  const float* bl2 = (const float*)d_in[11];
  float* outb = (float*)d_out;
  char* ws = (char*)d_ws;

  // carve (bytes), no aliasing:
  unsigned short* W1T  = (unsigned short*)(ws + 0);
  unsigned short* W2T  = (unsigned short*)(ws + 262144);
  unsigned short* Wl1T = (unsigned short*)(ws + 524288);
  unsigned short* Wl2T = (unsigned short*)(ws + 655360);
  unsigned short* vB   = (unsigned short*)(ws + 786432);     // 313 x 16KB tiles
  unsigned short* v_rm = (unsigned short*)(ws + 5914624);    // [10000][256] bf16
  int* counts  = (int*)(ws + 11034624);
  int* offsets = (int*)(ws + 11075584);
  int* cursor  = (int*)(ws + 11116544);
  int* srcbuf  = (int*)(ws + 11157504);                       // 1.28 MB
  unsigned short* avpb = (unsigned short*)(ws + 12437760);    // SPLIT x [N][256] bf16 (30.7MB)
  unsigned short* v2b  = (unsigned short*)(ws + 43157760);    // [N][256] bf16

  hipLaunchKernelGGL(k_conv, dim3(512), dim3(256), 0, stream,
                     W1, W2, Wl1, Wl2, W1T, W2T, Wl1T, Wl2T, vB, counts);
  hipLaunchKernelGGL(k_mlp, dim3(353), dim3(256), 0, stream,
                     vc, W1T, b1, W2T, b2, v_rm, vB, dst, counts);
  hipLaunchKernelGGL(k_av, dim3(475), dim3(512), 0, stream,
                     A, vB, avpb, counts, offsets, cursor);
  hipLaunchKernelGGL(k_out, dim3(353), dim3(256), 0, stream,
                     v_rm, avpb, Wl1T, bl1, Wl2T, bl2, v2b, outb,
                     src, dst, cursor, srcbuf);
  hipLaunchKernelGGL(k_gather, dim3((NN * 64 + 255) / 256), dim3(256), 0, stream,
                     v2b, offsets, srcbuf, outb);
}